// Round 1
// baseline (126.560 us; speedup 1.0000x reference)
//
#include <hip/hip_runtime.h>
#include <stdint.h>
#include <math.h>

typedef short v8s __attribute__((ext_vector_type(8)));
typedef float v4f __attribute__((ext_vector_type(4)));

#define DEVI static __device__ __forceinline__

static constexpr int Bn = 2;
static constexpr int Tn = 2048;
static constexpr int Cn = 1024;
static constexpr int Hn = 16;
static constexpr int Gn = 4;
static constexpr int Dn = 64;
static constexpr int NQKV = 1536;   // H*D + 2*G*D
static constexpr int WIN = 512;
static constexpr int SINKN = 4;
#define SCALE_L2E (0.125f * 1.4426950408889634f)   // D^-0.5 * log2(e)

DEVI unsigned short f2bf(float f) {
  unsigned u = __float_as_uint(f);
  u += 0x7fffu + ((u >> 16) & 1u);
  return (unsigned short)(u >> 16);
}
DEVI float bf2f(unsigned short h) { return __uint_as_float(((unsigned)h) << 16); }

// ---------------- fp32 -> bf16 convert (4 elems/thread) ----------------
__global__ __launch_bounds__(256) void k_convert(const float* __restrict__ in,
                                                 unsigned short* __restrict__ out, int n4) {
  int i = blockIdx.x * 256 + threadIdx.x;
  if (i >= n4) return;
  float4 v = ((const float4*)in)[i];
  ushort4 o;
  o.x = f2bf(v.x); o.y = f2bf(v.y); o.z = f2bf(v.z); o.w = f2bf(v.w);
  ((ushort4*)out)[i] = o;
}

// ------------- W[K][N] f32 -> Wt[N][K] bf16 (LDS-tiled transpose) -------------
__global__ __launch_bounds__(256) void k_transpose_w(const float* __restrict__ W,
                                                     unsigned short* __restrict__ Wt,
                                                     int K, int N) {
  __shared__ float tile[32][33];
  int n0 = blockIdx.x * 32, k0 = blockIdx.y * 32;
  int tx = threadIdx.x, ty = threadIdx.y;   // block (32,8)
  #pragma unroll
  for (int yy = 0; yy < 4; ++yy)
    tile[ty + yy * 8][tx] = W[(size_t)(k0 + ty + yy * 8) * N + n0 + tx];
  __syncthreads();
  #pragma unroll
  for (int yy = 0; yy < 4; ++yy)
    Wt[(size_t)(n0 + ty + yy * 8) * K + k0 + tx] = f2bf(tile[tx][ty + yy * 8]);
}

// ---------------- concat biases [bq|bk|bv] -> f32[1536] ----------------
__global__ void k_concat_bias(const float* __restrict__ bq, const float* __restrict__ bk,
                              const float* __restrict__ bv, float* __restrict__ out) {
  int i = blockIdx.x * 256 + threadIdx.x;
  if (i >= NQKV) return;
  out[i] = (i < 1024) ? bq[i] : (i < 1280 ? bk[i - 1024] : bv[i - 1280]);
}

// ---------------- RoPE cos/sin table [T][32] ----------------
__global__ void k_rope_table(const int* __restrict__ posp, float2* __restrict__ table) {
  int i = blockIdx.x * 256 + threadIdx.x;
  if (i >= Tn * 32) return;
  int t = i >> 5, d2 = i & 31;
  float inv = powf(10000.f, -(float)d2 / 32.f);
  float theta = (float)(posp[0] + t) * inv;
  float s, c;
  sincosf(theta, &s, &c);
  table[i] = make_float2(c, s);
}

// ---------------- in-place interleaved RoPE on q,k columns of qkv ----------------
__global__ __launch_bounds__(256) void k_rope(unsigned short* __restrict__ qkv,
                                              const float2* __restrict__ table) {
  int i = blockIdx.x * 256 + threadIdx.x;
  if (i >= 4096 * 640) return;
  int r = i / 640, pp = i - r * 640;            // 512 q-pairs + 128 k-pairs per row
  int col = (pp < 512) ? (2 * pp) : (1024 + 2 * (pp - 512));
  int d2 = pp & 31;
  int t = r & (Tn - 1);
  float2 cs = table[t * 32 + d2];
  unsigned* p = (unsigned*)(qkv + (size_t)r * NQKV + col);
  unsigned v = *p;
  float xe = bf2f((unsigned short)(v & 0xffff));
  float xo = bf2f((unsigned short)(v >> 16));
  float re = xe * cs.x - xo * cs.y;
  float ro = xe * cs.y + xo * cs.x;
  *p = (unsigned)f2bf(re) | ((unsigned)f2bf(ro) << 16);
}

// ---------------- GEMM: C[M][N] = A[M][K](bf16) * Bt[N][K]^T + bias ----------------
// 128x128 tile, BK=32, 4 waves (2x2), each wave 4x4 frags of 16x16x32.
template <bool F32OUT>
__global__ __launch_bounds__(256) void k_gemm_bt(const unsigned short* __restrict__ A,
                                                 const unsigned short* __restrict__ Bt,
                                                 const float* __restrict__ bias,
                                                 float* __restrict__ outF,
                                                 unsigned short* __restrict__ outH,
                                                 int M, int N, int K) {
  __shared__ char As[128 * 32 * 2];
  __shared__ char Bs[128 * 32 * 2];
  int m0 = blockIdx.y * 128, n0 = blockIdx.x * 128;
  int t = threadIdx.x, lane = t & 63, wave = t >> 6;
  int wm = wave >> 1, wn = wave & 1;
  int l15 = lane & 15, l4 = lane >> 4;
  v4f acc[4][4] = {};

  for (int k0 = 0; k0 < K; k0 += 32) {
    __syncthreads();
    #pragma unroll
    for (int p = 0; p < 2; ++p) {
      int cid = p * 256 + t;
      int row = cid >> 2, cc = cid & 3;
      const unsigned short* ga = A + (size_t)(m0 + row) * K + k0 + cc * 8;
      const unsigned short* gb = Bt + (size_t)(n0 + row) * K + k0 + cc * 8;
      __builtin_amdgcn_global_load_lds((const __attribute__((address_space(1))) void*)ga,
                                       (__attribute__((address_space(3))) void*)(As + p * 4096 + wave * 1024),
                                       16, 0, 0);
      __builtin_amdgcn_global_load_lds((const __attribute__((address_space(1))) void*)gb,
                                       (__attribute__((address_space(3))) void*)(Bs + p * 4096 + wave * 1024),
                                       16, 0, 0);
    }
    __syncthreads();
    v8s af[4], bfr[4];
    #pragma unroll
    for (int mi = 0; mi < 4; ++mi)
      af[mi] = *(const v8s*)(As + ((wm * 64 + mi * 16 + l15) * 32 + l4 * 8) * 2);
    #pragma unroll
    for (int ni = 0; ni < 4; ++ni)
      bfr[ni] = *(const v8s*)(Bs + ((wn * 64 + ni * 16 + l15) * 32 + l4 * 8) * 2);
    #pragma unroll
    for (int mi = 0; mi < 4; ++mi)
      #pragma unroll
      for (int ni = 0; ni < 4; ++ni)
        acc[mi][ni] = __builtin_amdgcn_mfma_f32_16x16x32_bf16(af[mi], bfr[ni], acc[mi][ni], 0, 0, 0);
  }

  #pragma unroll
  for (int mi = 0; mi < 4; ++mi) {
    #pragma unroll
    for (int ni = 0; ni < 4; ++ni) {
      int col = n0 + wn * 64 + ni * 16 + l15;
      float bv = bias[col];
      #pragma unroll
      for (int r = 0; r < 4; ++r) {
        int row = m0 + wm * 64 + mi * 16 + l4 * 4 + r;
        float v = acc[mi][ni][r] + bv;
        if (F32OUT) outF[(size_t)row * N + col] = v;
        else        outH[(size_t)row * N + col] = f2bf(v);
      }
    }
  }
}

// ---------------- Flash attention, GQA + sliding window + sink ----------------
// grid (T/64, H, B), 256 thr = 4 waves, each wave owns 16 q rows.
// Swapped QK^T: S^T = mfma(K,Q); O^T = mfma(V^T, P^T).
__global__ __launch_bounds__(256) void k_attn(const unsigned short* __restrict__ qkv,
                                              unsigned short* __restrict__ o) {
  __shared__ char Qs[8192];
  __shared__ char Ks[8192];
  __shared__ char Vs[8192];
  int qt0 = blockIdx.x * 64;
  int h = blockIdx.y, b = blockIdx.z, g = h >> 2;
  int t = threadIdx.x, lane = t & 63, wave = t >> 6;
  int l15 = lane & 15, l4 = lane >> 4;

  // stage Q tile [64 rows][64 dims], XOR-swizzled rows
  #pragma unroll
  for (int p = 0; p < 2; ++p) {
    int cid = p * 256 + t, r = cid >> 3, c = cid & 7;
    int4 v = *(const int4*)(qkv + (size_t)(b * Tn + qt0 + r) * NQKV + h * 64 + c * 8);
    *(int4*)(Qs + r * 128 + ((c ^ (r & 7)) << 4)) = v;
  }
  __syncthreads();
  v8s Qf[2];
  #pragma unroll
  for (int hf = 0; hf < 2; ++hf) {
    int r = wave * 16 + l15, c = hf * 4 + l4;
    Qf[hf] = *(const v8s*)(Qs + r * 128 + ((c ^ (r & 7)) << 4));
  }
  int qg = qt0 + wave * 16 + l15;      // this lane's q row (col of S^T)
  float m = -INFINITY, lsm = 0.f;
  v4f accO[4] = {};

  int jt_end = qt0 >> 6;
  int jt_start = (qt0 > WIN) ? ((qt0 - WIN) >> 6) : 0;
  int nIt = (jt_end - jt_start + 1) + (jt_start > 0 ? 1 : 0);

  for (int it = 0; it < nIt; ++it) {
    int jt = (jt_start > 0) ? ((it == 0) ? 0 : (jt_start + it - 1)) : (jt_start + it);
    int j0 = jt * 64;
    __syncthreads();
    // stage K tile [64 keys][64 dims], swizzled
    #pragma unroll
    for (int p = 0; p < 2; ++p) {
      int cid = p * 256 + t, r = cid >> 3, c = cid & 7;
      int4 v = *(const int4*)(qkv + (size_t)(b * Tn + j0 + r) * NQKV + 1024 + g * 64 + c * 8);
      *(int4*)(Ks + r * 128 + ((c ^ (r & 7)) << 4)) = v;
    }
    // stage V transposed: Vs[d][key], swizzled rows (d)
    #pragma unroll
    for (int p = 0; p < 2; ++p) {
      int j = t >> 2, dbase = p * 32 + (t & 3) * 8;
      v8s v = *(const v8s*)(qkv + (size_t)(b * Tn + j0 + j) * NQKV + 1280 + g * 64 + dbase);
      #pragma unroll
      for (int i2 = 0; i2 < 8; ++i2) {
        int d = dbase + i2;
        *(short*)(Vs + d * 128 + ((j * 2) ^ ((d & 7) << 4))) = v[i2];
      }
    }
    __syncthreads();

    // S^T[key][q] : 4 key-blocks of 16
    v4f s[4];
    #pragma unroll
    for (int kb = 0; kb < 4; ++kb) {
      int r = kb * 16 + l15;
      v8s kf0 = *(const v8s*)(Ks + r * 128 + (((l4) ^ (r & 7)) << 4));
      v8s kf1 = *(const v8s*)(Ks + r * 128 + (((4 + l4) ^ (r & 7)) << 4));
      v4f z = {};
      z = __builtin_amdgcn_mfma_f32_16x16x32_bf16(kf0, Qf[0], z, 0, 0, 0);
      s[kb] = __builtin_amdgcn_mfma_f32_16x16x32_bf16(kf1, Qf[1], z, 0, 0, 0);
    }

    // mask + scale (exp2 domain), tile max
    float pv[4][4];
    float mt = -INFINITY;
    #pragma unroll
    for (int kb = 0; kb < 4; ++kb)
      #pragma unroll
      for (int r = 0; r < 4; ++r) {
        int j = j0 + kb * 16 + l4 * 4 + r;
        float sv = s[kb][r] * SCALE_L2E;
        bool valid = (j <= qg) && ((j >= qg - WIN) || (j < SINKN));
        sv = valid ? sv : -1e30f;
        pv[kb][r] = sv;
        mt = fmaxf(mt, sv);
      }
    mt = fmaxf(mt, __shfl_xor(mt, 16));
    mt = fmaxf(mt, __shfl_xor(mt, 32));
    float mnew = fmaxf(m, mt);
    float alpha = exp2f(m - mnew);     // first tile: exp2(-inf)=0
    float lsum = 0.f;
    unsigned pk[4][2];
    #pragma unroll
    for (int kb = 0; kb < 4; ++kb) {
      float p0 = exp2f(pv[kb][0] - mnew);
      float p1 = exp2f(pv[kb][1] - mnew);
      float p2 = exp2f(pv[kb][2] - mnew);
      float p3 = exp2f(pv[kb][3] - mnew);
      lsum += p0 + p1 + p2 + p3;
      pk[kb][0] = (unsigned)f2bf(p0) | ((unsigned)f2bf(p1) << 16);
      pk[kb][1] = (unsigned)f2bf(p2) | ((unsigned)f2bf(p3) << 16);
    }
    lsum += __shfl_xor(lsum, 16);
    lsum += __shfl_xor(lsum, 32);
    lsm = lsm * alpha + lsum;
    m = mnew;
    #pragma unroll
    for (int db = 0; db < 4; ++db) {
      accO[db][0] *= alpha; accO[db][1] *= alpha;
      accO[db][2] *= alpha; accO[db][3] *= alpha;
    }

    // build P^T B-frags via shfl, then PV
    int src0 = ((2 * (l4 & 1)) << 4) | l15;
    int src1 = src0 + 16;
    bool hiSel = (l4 >> 1) & 1;
    #pragma unroll
    for (int kc = 0; kc < 2; ++kc) {
      int A0 = __shfl((int)pk[kc * 2][0], src0);
      int A1 = __shfl((int)pk[kc * 2][1], src0);
      int A2 = __shfl((int)pk[kc * 2][0], src1);
      int A3 = __shfl((int)pk[kc * 2][1], src1);
      int B0 = __shfl((int)pk[kc * 2 + 1][0], src0);
      int B1 = __shfl((int)pk[kc * 2 + 1][1], src0);
      int B2 = __shfl((int)pk[kc * 2 + 1][0], src1);
      int B3 = __shfl((int)pk[kc * 2 + 1][1], src1);
      union { int i[4]; v8s v; } u;
      u.i[0] = hiSel ? B0 : A0;
      u.i[1] = hiSel ? B1 : A1;
      u.i[2] = hiSel ? B2 : A2;
      u.i[3] = hiSel ? B3 : A3;
      #pragma unroll
      for (int db = 0; db < 4; ++db) {
        int d = db * 16 + l15;
        int c = kc * 4 + l4;
        v8s vf = *(const v8s*)(Vs + d * 128 + ((c ^ (d & 7)) << 4));
        accO[db] = __builtin_amdgcn_mfma_f32_16x16x32_bf16(vf, u.v, accO[db], 0, 0, 0);
      }
    }
  }

  // normalize + write O[t][h*64+d] bf16
  float inv = 1.f / lsm;
  size_t orow = (size_t)(b * Tn + qg) * 1024 + h * 64;
  #pragma unroll
  for (int db = 0; db < 4; ++db) {
    int d0 = db * 16 + l4 * 4;
    ushort4 ov;
    ov.x = f2bf(accO[db][0] * inv);
    ov.y = f2bf(accO[db][1] * inv);
    ov.z = f2bf(accO[db][2] * inv);
    ov.w = f2bf(accO[db][3] * inv);
    *(ushort4*)(o + orow + d0) = ov;
  }
}

extern "C" void kernel_launch(void* const* d_in, const int* in_sizes, int n_in,
                              void* d_out, int out_size, void* d_ws, size_t ws_size,
                              hipStream_t stream) {
  const float* x  = (const float*)d_in[0];
  const float* Wq = (const float*)d_in[1];
  const float* bq = (const float*)d_in[2];
  const float* Wk = (const float*)d_in[3];
  const float* bk = (const float*)d_in[4];
  const float* Wv = (const float*)d_in[5];
  const float* bv = (const float*)d_in[6];
  const float* Wo = (const float*)d_in[7];
  const float* bo = (const float*)d_in[8];
  const int*   pos = (const int*)d_in[9];
  float* out = (float*)d_out;

  char* ws = (char*)d_ws;
  unsigned short* xb      = (unsigned short*)(ws);                       // 4096*1024*2 = 8388608
  unsigned short* wt_qkv  = (unsigned short*)(ws + 8388608);             // 1536*1024*2 = 3145728
  unsigned short* wt_o    = (unsigned short*)(ws + 8388608 + 3145728);   // 1024*1024*2 = 2097152
  float*          bias_q  = (float*)(ws + 8388608 + 3145728 + 2097152);  // 6144
  float2*         table   = (float2*)(ws + 8388608 + 3145728 + 2097152 + 6144);  // 524288
  unsigned short* qkvb    = (unsigned short*)(ws + 8388608 + 3145728 + 2097152 + 6144 + 524288); // 12582912
  unsigned short* attno   = (unsigned short*)(ws + 8388608 + 3145728 + 2097152 + 6144 + 524288 + 12582912); // 8388608

  // x -> bf16
  k_convert<<<4096, 256, 0, stream>>>(x, xb, 4096 * 1024 / 4);
  // weight transposes (concat q|k|v)
  k_transpose_w<<<dim3(32, 32), dim3(32, 8), 0, stream>>>(Wq, wt_qkv, 1024, 1024);
  k_transpose_w<<<dim3(8, 32),  dim3(32, 8), 0, stream>>>(Wk, wt_qkv + 1024 * 1024, 1024, 256);
  k_transpose_w<<<dim3(8, 32),  dim3(32, 8), 0, stream>>>(Wv, wt_qkv + 1280 * 1024, 1024, 256);
  k_transpose_w<<<dim3(32, 32), dim3(32, 8), 0, stream>>>(Wo, wt_o, 1024, 1024);
  k_concat_bias<<<6, 256, 0, stream>>>(bq, bk, bv, bias_q);
  k_rope_table<<<256, 256, 0, stream>>>(pos, table);
  // qkv = x @ [Wq|Wk|Wv] + bias  (bf16 out)
  k_gemm_bt<false><<<dim3(12, 32), 256, 0, stream>>>(xb, wt_qkv, bias_q, nullptr, qkvb,
                                                     4096, NQKV, 1024);
  // RoPE q,k in place
  k_rope<<<10240, 256, 0, stream>>>(qkvb, table);
  // attention
  k_attn<<<dim3(32, 16, 2), 256, 0, stream>>>(qkvb, attno);
  // out = attn @ Wo + bo  (f32 out)
  k_gemm_bt<true><<<dim3(8, 32), 256, 0, stream>>>(attno, wt_o, bo, out, nullptr,
                                                   4096, 1024, 1024);
}

// Round 2
// 113.652 us; speedup vs baseline: 1.1136x; 1.1136x over previous
//
#include <hip/hip_runtime.h>
#include <stdint.h>
#include <math.h>

typedef short v8s __attribute__((ext_vector_type(8)));
typedef float v4f __attribute__((ext_vector_type(4)));

#define DEVI static __device__ __forceinline__
#define AS1 __attribute__((address_space(1)))
#define AS3 __attribute__((address_space(3)))

static constexpr int Bn = 2;
static constexpr int Tn = 2048;
static constexpr int Hn = 16;
static constexpr int Gn = 4;
static constexpr int NQKV = 1536;   // H*D + 2*G*D
static constexpr int WIN = 512;
static constexpr int SINKN = 4;
#define SCALE_L2E (0.125f * 1.4426950408889634f)   // D^-0.5 * log2(e), folded into Wq/bq

DEVI unsigned short f2bf(float f) {
  unsigned u = __float_as_uint(f);
  u += 0x7fffu + ((u >> 16) & 1u);
  return (unsigned short)(u >> 16);
}
DEVI float bf2f(unsigned short h) { return __uint_as_float(((unsigned)h) << 16); }
// pack two f32 -> bf16x2 by truncation: low short = lo, high short = hi
DEVI unsigned pack_bf2(float hi, float lo) {
  return __builtin_amdgcn_perm(__float_as_uint(hi), __float_as_uint(lo), 0x07060302u);
}

// ---------------- fp32 -> bf16 convert (4 elems/thread) ----------------
__global__ __launch_bounds__(256) void k_convert(const float* __restrict__ in,
                                                 unsigned short* __restrict__ out, int n4) {
  int i = blockIdx.x * 256 + threadIdx.x;
  if (i >= n4) return;
  float4 v = ((const float4*)in)[i];
  ushort4 o;
  o.x = f2bf(v.x); o.y = f2bf(v.y); o.z = f2bf(v.z); o.w = f2bf(v.w);
  ((ushort4*)out)[i] = o;
}

// ------------- W[K][N] f32 -> Wt[N][K] bf16 * scale (LDS-tiled transpose) -------------
__global__ __launch_bounds__(256) void k_transpose_w(const float* __restrict__ W,
                                                     unsigned short* __restrict__ Wt,
                                                     int K, int N, float scale) {
  __shared__ float tile[32][33];
  int n0 = blockIdx.x * 32, k0 = blockIdx.y * 32;
  int tx = threadIdx.x, ty = threadIdx.y;   // block (32,8)
  #pragma unroll
  for (int yy = 0; yy < 4; ++yy)
    tile[ty + yy * 8][tx] = W[(size_t)(k0 + ty + yy * 8) * N + n0 + tx];
  __syncthreads();
  #pragma unroll
  for (int yy = 0; yy < 4; ++yy)
    Wt[(size_t)(n0 + ty + yy * 8) * K + k0 + tx] = f2bf(tile[tx][ty + yy * 8] * scale);
}

// ---------------- concat biases [bq*scale|bk|bv] -> f32[1536] ----------------
__global__ void k_concat_bias(const float* __restrict__ bq, const float* __restrict__ bk,
                              const float* __restrict__ bv, float* __restrict__ out) {
  int i = blockIdx.x * 256 + threadIdx.x;
  if (i >= NQKV) return;
  out[i] = (i < 1024) ? bq[i] * SCALE_L2E : (i < 1280 ? bk[i - 1024] : bv[i - 1280]);
}

// ---------------- RoPE cos/sin table [T][32] ----------------
__global__ void k_rope_table(const int* __restrict__ posp, float2* __restrict__ table) {
  int i = blockIdx.x * 256 + threadIdx.x;
  if (i >= Tn * 32) return;
  int t = i >> 5, d2 = i & 31;
  float inv = powf(10000.f, -(float)d2 / 32.f);
  float theta = (float)(posp[0] + t) * inv;
  float s, c;
  sincosf(theta, &s, &c);
  table[i] = make_float2(c, s);
}

// ---------------- in-place interleaved RoPE on q,k columns of qkv ----------------
__global__ __launch_bounds__(256) void k_rope(unsigned short* __restrict__ qkv,
                                              const float2* __restrict__ table) {
  int i = blockIdx.x * 256 + threadIdx.x;
  if (i >= 4096 * 640) return;
  int r = i / 640, pp = i - r * 640;            // 512 q-pairs + 128 k-pairs per row
  int col = (pp < 512) ? (2 * pp) : (1024 + 2 * (pp - 512));
  int d2 = pp & 31;
  int t = r & (Tn - 1);
  float2 cs = table[t * 32 + d2];
  unsigned* p = (unsigned*)(qkv + (size_t)r * NQKV + col);
  unsigned v = *p;
  float xe = bf2f((unsigned short)(v & 0xffff));
  float xo = bf2f((unsigned short)(v >> 16));
  float re = xe * cs.x - xo * cs.y;
  float ro = xe * cs.y + xo * cs.x;
  *p = (unsigned)f2bf(re) | ((unsigned)f2bf(ro) << 16);
}

// ---------------- GEMM: C[M][N] = A[M][K](bf16) * Bt[N][K]^T + bias ----------------
// 128x128 tile, BK=32, 4 waves (2x2), 2-phase prefetch double-buffer.
// F32OUT=false: n0<1280 -> bf16 to outH[row][col]; n0>=1280 -> v cols transposed to vtH[b][g][d][t].
template <bool F32OUT>
__global__ __launch_bounds__(256) void k_gemm_bt(const unsigned short* __restrict__ A,
                                                 const unsigned short* __restrict__ Bt,
                                                 const float* __restrict__ bias,
                                                 float* __restrict__ outF,
                                                 unsigned short* __restrict__ outH,
                                                 unsigned short* __restrict__ vtH,
                                                 int M, int N, int K) {
  __shared__ char As[2][8192];
  __shared__ char Bs[2][8192];
  int m0 = blockIdx.y * 128, n0 = blockIdx.x * 128;
  int t = threadIdx.x, lane = t & 63, wave = t >> 6;
  int wm = wave >> 1, wn = wave & 1;
  int l15 = lane & 15, l4 = lane >> 4;
  v4f acc[4][4] = {};
  int NS = K >> 5;

  auto stage = [&](int buf, int k0) {
    #pragma unroll
    for (int p = 0; p < 2; ++p) {
      int cid = p * 256 + t;
      int row = cid >> 2, cc = cid & 3;
      const unsigned short* ga = A + (size_t)(m0 + row) * K + k0 + cc * 8;
      const unsigned short* gb = Bt + (size_t)(n0 + row) * K + k0 + cc * 8;
      __builtin_amdgcn_global_load_lds((const AS1 void*)ga,
                                       (AS3 void*)(&As[buf][0] + p * 4096 + wave * 1024), 16, 0, 0);
      __builtin_amdgcn_global_load_lds((const AS1 void*)gb,
                                       (AS3 void*)(&Bs[buf][0] + p * 4096 + wave * 1024), 16, 0, 0);
    }
  };

  stage(0, 0);
  __syncthreads();
  for (int ks = 0; ks < NS; ++ks) {
    int cur = ks & 1;
    if (ks + 1 < NS) stage(cur ^ 1, (ks + 1) << 5);
    v8s af[4], bfr[4];
    #pragma unroll
    for (int mi = 0; mi < 4; ++mi)
      af[mi] = *(const v8s*)(&As[cur][0] + ((wm * 64 + mi * 16 + l15) * 32 + l4 * 8) * 2);
    #pragma unroll
    for (int ni = 0; ni < 4; ++ni)
      bfr[ni] = *(const v8s*)(&Bs[cur][0] + ((wn * 64 + ni * 16 + l15) * 32 + l4 * 8) * 2);
    #pragma unroll
    for (int mi = 0; mi < 4; ++mi)
      #pragma unroll
      for (int ni = 0; ni < 4; ++ni)
        acc[mi][ni] = __builtin_amdgcn_mfma_f32_16x16x32_bf16(af[mi], bfr[ni], acc[mi][ni], 0, 0, 0);
    __syncthreads();
  }

  if (!F32OUT && n0 >= 1280) {
    // v columns -> Vt[b][g][d][t], 4 contiguous t per lane
    #pragma unroll
    for (int mi = 0; mi < 4; ++mi) {
      #pragma unroll
      for (int ni = 0; ni < 4; ++ni) {
        int col = n0 + wn * 64 + ni * 16 + l15;
        float bv = bias[col];
        int c2 = col - 1280;
        int gg = c2 >> 6, dd = c2 & 63;
        int row = m0 + wm * 64 + mi * 16 + l4 * 4;
        int bb = row >> 11, tt = row & 2047;
        ushort4 ov;
        ov.x = f2bf(acc[mi][ni][0] + bv);
        ov.y = f2bf(acc[mi][ni][1] + bv);
        ov.z = f2bf(acc[mi][ni][2] + bv);
        ov.w = f2bf(acc[mi][ni][3] + bv);
        *(ushort4*)(vtH + ((size_t)((bb * Gn + gg) * 64 + dd)) * Tn + tt) = ov;
      }
    }
  } else {
    #pragma unroll
    for (int mi = 0; mi < 4; ++mi) {
      #pragma unroll
      for (int ni = 0; ni < 4; ++ni) {
        int col = n0 + wn * 64 + ni * 16 + l15;
        float bv = bias[col];
        #pragma unroll
        for (int r = 0; r < 4; ++r) {
          int row = m0 + wm * 64 + mi * 16 + l4 * 4 + r;
          float v = acc[mi][ni][r] + bv;
          if (F32OUT) outF[(size_t)row * N + col] = v;
          else        outH[(size_t)row * N + col] = f2bf(v);
        }
      }
    }
  }
}

// ---------------- Flash attention, GQA + sliding window + sink ----------------
// grid (T/128, H, B), 512 thr = 8 waves, wave w owns q rows [qt0+16w, qt0+16w+16).
// Swapped QK^T: S^T = mfma(K,Q); O^T = mfma(V^T, P^T). K and V^T double-buffered
// in LDS via global_load_lds with pre-swizzled source columns.
__global__ __launch_bounds__(512) void k_attn(const unsigned short* __restrict__ qkv,
                                              const unsigned short* __restrict__ vt,
                                              unsigned short* __restrict__ o) {
  __shared__ char smem[2 * 16384];    // per buf: K tile 8KB | V^T tile 8KB
  int qt0 = blockIdx.x * 128;
  int h = blockIdx.y, b = blockIdx.z, g = h >> 2;
  int t = threadIdx.x, lane = t & 63, wave = t >> 6;
  int l15 = lane & 15, l4 = lane >> 4;
  int qw0 = qt0 + wave * 16;

  // tile schedule
  int jt_end = (qt0 + 127) >> 6;
  int wstart = (qt0 > WIN) ? ((qt0 - WIN) >> 6) : 0;
  int nIt = (wstart > 0) ? (jt_end - wstart + 2) : (jt_end + 1);

  // staging source coords (per thread, 1 x 16B per matrix)
  int sr = t >> 3, sc = t & 7;
  int scs = (sc ^ (sr & 7)) << 3;   // pre-swizzled element offset
  const unsigned short* gkb = qkv + (size_t)(b * Tn + sr) * NQKV + 1024 + g * 64 + scs;
  const unsigned short* gvb = vt + ((size_t)((b * Gn + g) * 64 + sr)) * Tn + scs;

  auto stageKV = [&](int buf, int j0) {
    __builtin_amdgcn_global_load_lds((const AS1 void*)(gkb + (size_t)j0 * NQKV),
                                     (AS3 void*)(smem + buf * 16384 + wave * 1024), 16, 0, 0);
    __builtin_amdgcn_global_load_lds((const AS1 void*)(gvb + j0),
                                     (AS3 void*)(smem + buf * 16384 + 8192 + wave * 1024), 16, 0, 0);
  };

  auto jt_of = [&](int it) { return (wstart > 0) ? (it == 0 ? 0 : wstart + it - 1) : it; };

  stageKV(0, jt_of(0) << 6);

  // Q fragments direct from global (post-RoPE, scale pre-folded)
  v8s Qf[2];
  #pragma unroll
  for (int hf = 0; hf < 2; ++hf)
    Qf[hf] = *(const v8s*)(qkv + (size_t)(b * Tn + qw0 + l15) * NQKV + h * 64 + hf * 32 + l4 * 8);

  float m = -INFINITY, lsm = 0.f;
  v4f accO[4] = {};

  __syncthreads();

  for (int it = 0; it < nIt; ++it) {
    int cur = it & 1;
    if (it + 1 < nIt) stageKV(cur ^ 1, jt_of(it + 1) << 6);
    int j0 = jt_of(it) << 6;

    bool skip = (j0 > qw0 + 15) || ((j0 + 63 < qw0 - WIN) && (j0 >= SINKN));
    if (!skip) {
      const char* Kb = smem + cur * 16384;
      const char* Vb = Kb + 8192;
      // S^T[key][q]
      v4f s[4];
      #pragma unroll
      for (int kb = 0; kb < 4; ++kb) {
        int r = kb * 16 + l15;
        v8s kf0 = *(const v8s*)(Kb + r * 128 + ((l4 ^ (r & 7)) << 4));
        v8s kf1 = *(const v8s*)(Kb + r * 128 + (((4 + l4) ^ (r & 7)) << 4));
        v4f z = {};
        z = __builtin_amdgcn_mfma_f32_16x16x32_bf16(kf0, Qf[0], z, 0, 0, 0);
        s[kb] = __builtin_amdgcn_mfma_f32_16x16x32_bf16(kf1, Qf[1], z, 0, 0, 0);
      }
      bool needMask = !((j0 + 63 <= qw0) && (j0 >= qw0 + 15 - WIN));
      if (needMask) {
        #pragma unroll
        for (int kb = 0; kb < 4; ++kb)
          #pragma unroll
          for (int r = 0; r < 4; ++r) {
            int j = j0 + kb * 16 + l4 * 4 + r;
            int qg = qw0 + l15;
            bool valid = (j <= qg) && ((j >= qg - WIN) || (j < SINKN));
            s[kb][r] = valid ? s[kb][r] : -1e30f;
          }
      }
      float mt = -1e30f;
      #pragma unroll
      for (int kb = 0; kb < 4; ++kb)
        #pragma unroll
        for (int r = 0; r < 4; ++r) mt = fmaxf(mt, s[kb][r]);
      mt = fmaxf(mt, __shfl_xor(mt, 16));
      mt = fmaxf(mt, __shfl_xor(mt, 32));
      if (!__all(mt <= m + 8.f)) {      // T13 defer-max
        float mnew = fmaxf(m, mt);
        float alpha = exp2f(m - mnew);  // first tile: exp2(-inf)=0
        lsm *= alpha;
        #pragma unroll
        for (int db = 0; db < 4; ++db) {
          accO[db][0] *= alpha; accO[db][1] *= alpha;
          accO[db][2] *= alpha; accO[db][3] *= alpha;
        }
        m = mnew;
      }
      float lsum = 0.f;
      unsigned pk[4][2];
      #pragma unroll
      for (int kb = 0; kb < 4; ++kb) {
        float p0 = exp2f(s[kb][0] - m);
        float p1 = exp2f(s[kb][1] - m);
        float p2 = exp2f(s[kb][2] - m);
        float p3 = exp2f(s[kb][3] - m);
        lsum += (p0 + p1) + (p2 + p3);
        pk[kb][0] = pack_bf2(p1, p0);
        pk[kb][1] = pack_bf2(p3, p2);
      }
      lsum += __shfl_xor(lsum, 16);
      lsum += __shfl_xor(lsum, 32);
      lsm += lsum;

      // P^T B-frags via shfl, then PV
      int src0 = ((2 * (l4 & 1)) << 4) | l15;
      int src1 = src0 + 16;
      bool hiSel = (l4 >> 1) & 1;
      #pragma unroll
      for (int kc = 0; kc < 2; ++kc) {
        int A0 = __shfl((int)pk[kc * 2][0], src0);
        int A1 = __shfl((int)pk[kc * 2][1], src0);
        int A2 = __shfl((int)pk[kc * 2][0], src1);
        int A3 = __shfl((int)pk[kc * 2][1], src1);
        int B0 = __shfl((int)pk[kc * 2 + 1][0], src0);
        int B1 = __shfl((int)pk[kc * 2 + 1][1], src0);
        int B2 = __shfl((int)pk[kc * 2 + 1][0], src1);
        int B3 = __shfl((int)pk[kc * 2 + 1][1], src1);
        union { int i[4]; v8s v; } u;
        u.i[0] = hiSel ? B0 : A0;
        u.i[1] = hiSel ? B1 : A1;
        u.i[2] = hiSel ? B2 : A2;
        u.i[3] = hiSel ? B3 : A3;
        #pragma unroll
        for (int db = 0; db < 4; ++db) {
          int d = db * 16 + l15;
          v8s vf = *(const v8s*)(Vb + d * 128 + (((kc * 4 + l4) ^ (d & 7)) << 4));
          accO[db] = __builtin_amdgcn_mfma_f32_16x16x32_bf16(vf, u.v, accO[db], 0, 0, 0);
        }
      }
    }
    __syncthreads();
  }

  // normalize + write O[t][h*64+d] bf16
  float inv = 1.f / lsm;
  size_t orow = (size_t)(b * Tn + qw0 + l15) * 1024 + h * 64;
  #pragma unroll
  for (int db = 0; db < 4; ++db) {
    int d0 = db * 16 + l4 * 4;
    ushort4 ov;
    ov.x = f2bf(accO[db][0] * inv);
    ov.y = f2bf(accO[db][1] * inv);
    ov.z = f2bf(accO[db][2] * inv);
    ov.w = f2bf(accO[db][3] * inv);
    *(ushort4*)(o + orow + d0) = ov;
  }
}

extern "C" void kernel_launch(void* const* d_in, const int* in_sizes, int n_in,
                              void* d_out, int out_size, void* d_ws, size_t ws_size,
                              hipStream_t stream) {
  const float* x  = (const float*)d_in[0];
  const float* Wq = (const float*)d_in[1];
  const float* bq = (const float*)d_in[2];
  const float* Wk = (const float*)d_in[3];
  const float* bk = (const float*)d_in[4];
  const float* Wv = (const float*)d_in[5];
  const float* bv = (const float*)d_in[6];
  const float* Wo = (const float*)d_in[7];
  const float* bo = (const float*)d_in[8];
  const int*   pos = (const int*)d_in[9];
  float* out = (float*)d_out;

  char* ws = (char*)d_ws;
  unsigned short* xb      = (unsigned short*)(ws);                        // 8388608 B (reused as attno)
  unsigned short* wt_qkv  = (unsigned short*)(ws + 8388608);              // 3145728 B
  unsigned short* wt_o    = (unsigned short*)(ws + 11534336);             // 2097152 B
  float*          bias_q  = (float*)(ws + 13631488);                      // 6144 B
  float2*         table   = (float2*)(ws + 13637632);                     // 524288 B
  unsigned short* qkvb    = (unsigned short*)(ws + 14161920);             // 12582912 B
  unsigned short* vt      = (unsigned short*)(ws + 26744832);             // 2097152 B
  unsigned short* attno   = xb;                                           // reuse (x bf16 dead after GEMM1)

  // x -> bf16
  k_convert<<<4096, 256, 0, stream>>>(x, xb, 4096 * 1024 / 4);
  // weight transposes (concat q|k|v); SCALE*log2e folded into Wq
  k_transpose_w<<<dim3(32, 32), dim3(32, 8), 0, stream>>>(Wq, wt_qkv, 1024, 1024, SCALE_L2E);
  k_transpose_w<<<dim3(8, 32),  dim3(32, 8), 0, stream>>>(Wk, wt_qkv + 1024 * 1024, 1024, 256, 1.f);
  k_transpose_w<<<dim3(8, 32),  dim3(32, 8), 0, stream>>>(Wv, wt_qkv + 1280 * 1024, 1024, 256, 1.f);
  k_transpose_w<<<dim3(32, 32), dim3(32, 8), 0, stream>>>(Wo, wt_o, 1024, 1024, 1.f);
  k_concat_bias<<<6, 256, 0, stream>>>(bq, bk, bv, bias_q);
  k_rope_table<<<256, 256, 0, stream>>>(pos, table);
  // qkv = x @ [Wq|Wk|Wv] + bias; q,k -> qkvb (bf16), v -> vt transposed
  k_gemm_bt<false><<<dim3(12, 32), 256, 0, stream>>>(xb, wt_qkv, bias_q, nullptr, qkvb, vt,
                                                     4096, NQKV, 1024);
  // RoPE q,k in place
  k_rope<<<10240, 256, 0, stream>>>(qkvb, table);
  // attention
  k_attn<<<dim3(16, 16, 2), 512, 0, stream>>>(qkvb, vt, attno);
  // out = attn @ Wo + bo  (f32 out)
  k_gemm_bt<true><<<dim3(8, 32), 256, 0, stream>>>(attno, wt_o, bo, out, nullptr, nullptr,
                                                   4096, 1024, 1024);
}

// Round 3
// 107.323 us; speedup vs baseline: 1.1792x; 1.0590x over previous
//
#include <hip/hip_runtime.h>
#include <stdint.h>
#include <math.h>

typedef short v8s __attribute__((ext_vector_type(8)));
typedef float v4f __attribute__((ext_vector_type(4)));

#define DEVI static __device__ __forceinline__
#define AS1 __attribute__((address_space(1)))
#define AS3 __attribute__((address_space(3)))

static constexpr int Bn = 2;
static constexpr int Tn = 2048;
static constexpr int Hn = 16;
static constexpr int Gn = 4;
static constexpr int NQKV = 1536;   // H*D + 2*G*D
static constexpr int WIN = 512;
static constexpr int SINKN = 4;
#define SCALE_L2E (0.125f * 1.4426950408889634f)   // D^-0.5 * log2(e), folded into Wq/bq

DEVI unsigned short f2bf(float f) {
  unsigned u = __float_as_uint(f);
  u += 0x7fffu + ((u >> 16) & 1u);
  return (unsigned short)(u >> 16);
}
DEVI float bf2f(unsigned short h) { return __uint_as_float(((unsigned)h) << 16); }
// pack two f32 -> bf16x2 by truncation: low short = lo, high short = hi
DEVI unsigned pack_bf2(float hi, float lo) {
  return __builtin_amdgcn_perm(__float_as_uint(hi), __float_as_uint(lo), 0x07060302u);
}

// ---------------- fp32 -> bf16 convert (4 elems/thread) ----------------
__global__ __launch_bounds__(256) void k_convert(const float* __restrict__ in,
                                                 unsigned short* __restrict__ out, int n4) {
  int i = blockIdx.x * 256 + threadIdx.x;
  if (i >= n4) return;
  float4 v = ((const float4*)in)[i];
  ushort4 o;
  o.x = f2bf(v.x); o.y = f2bf(v.y); o.z = f2bf(v.z); o.w = f2bf(v.w);
  ((ushort4*)out)[i] = o;
}

// ------------- all four W[K][N] f32 -> Wt[N][K] bf16 * scale, one launch -------------
// z: 0=Wq(scale) 1=Wk 2=Wv 3=Wo
__global__ __launch_bounds__(256) void k_transpose_all(const float* __restrict__ Wq,
                                                       const float* __restrict__ Wk,
                                                       const float* __restrict__ Wv,
                                                       const float* __restrict__ Wo,
                                                       unsigned short* __restrict__ wt_qkv,
                                                       unsigned short* __restrict__ wt_o) {
  int z = blockIdx.z;
  const float* W; unsigned short* Wt; int N; float scale = 1.f;
  if (z == 0)      { W = Wq; Wt = wt_qkv;                 N = 1024; scale = SCALE_L2E; }
  else if (z == 1) { W = Wk; Wt = wt_qkv + 1024 * 1024;   N = 256; }
  else if (z == 2) { W = Wv; Wt = wt_qkv + 1280 * 1024;   N = 256; }
  else             { W = Wo; Wt = wt_o;                   N = 1024; }
  int n0 = blockIdx.x * 32, k0 = blockIdx.y * 32;
  if (n0 >= N) return;
  __shared__ float tile[32][33];
  int tx = threadIdx.x, ty = threadIdx.y;   // block (32,8)
  #pragma unroll
  for (int yy = 0; yy < 4; ++yy)
    tile[ty + yy * 8][tx] = W[(size_t)(k0 + ty + yy * 8) * N + n0 + tx];
  __syncthreads();
  #pragma unroll
  for (int yy = 0; yy < 4; ++yy)
    Wt[(size_t)(n0 + ty + yy * 8) * 1024 + k0 + tx] = f2bf(tile[tx][ty + yy * 8] * scale);
}

// ---------------- RoPE table [T][32] (cos,sin) + concat biases, one launch ----------------
__global__ __launch_bounds__(256) void k_table_bias(const int* __restrict__ posp,
                                                    float2* __restrict__ table,
                                                    const float* __restrict__ bq,
                                                    const float* __restrict__ bk,
                                                    const float* __restrict__ bv,
                                                    float* __restrict__ biasout) {
  int i = blockIdx.x * 256 + threadIdx.x;
  if (i < Tn * 32) {
    int t = i >> 5, d2 = i & 31;
    float inv = powf(10000.f, -(float)d2 / 32.f);
    float theta = (float)(posp[0] + t) * inv;
    float s, c;
    sincosf(theta, &s, &c);
    table[i] = make_float2(c, s);
  }
  if (i < NQKV)
    biasout[i] = (i < 1024) ? bq[i] * SCALE_L2E : (i < 1280 ? bk[i - 1024] : bv[i - 1280]);
}

// ---------------- GEMM: C[M][N] = A[M][K](bf16) * Bt[N][K]^T + bias ----------------
// 128x128 tile, BK=32, 4 waves (2x2), m97 single-buffer 2-barrier structure.
// F32OUT=false: n0<1280 -> RoPE applied (interleaved pairs via shfl_xor(1)), bf16 row-major;
//               n0>=1280 -> v cols transposed to vtH[b][g][d][t].
template <bool F32OUT>
__global__ __launch_bounds__(256) void k_gemm_bt(const unsigned short* __restrict__ A,
                                                 const unsigned short* __restrict__ Bt,
                                                 const float* __restrict__ bias,
                                                 const float2* __restrict__ table,
                                                 float* __restrict__ outF,
                                                 unsigned short* __restrict__ outH,
                                                 unsigned short* __restrict__ vtH,
                                                 int M, int N, int K) {
  __shared__ char As[8192];
  __shared__ char Bs[8192];
  int m0 = blockIdx.y * 128, n0 = blockIdx.x * 128;
  int t = threadIdx.x, lane = t & 63, wave = t >> 6;
  int wm = wave >> 1, wn = wave & 1;
  int l15 = lane & 15, l4 = lane >> 4;
  v4f acc[4][4] = {};

  for (int k0 = 0; k0 < K; k0 += 32) {
    __syncthreads();
    #pragma unroll
    for (int p = 0; p < 2; ++p) {
      int cid = p * 256 + t;
      int row = cid >> 2, cc = cid & 3;
      const unsigned short* ga = A + (size_t)(m0 + row) * K + k0 + cc * 8;
      const unsigned short* gb = Bt + (size_t)(n0 + row) * K + k0 + cc * 8;
      __builtin_amdgcn_global_load_lds((const AS1 void*)ga,
                                       (AS3 void*)(As + p * 4096 + wave * 1024), 16, 0, 0);
      __builtin_amdgcn_global_load_lds((const AS1 void*)gb,
                                       (AS3 void*)(Bs + p * 4096 + wave * 1024), 16, 0, 0);
    }
    __syncthreads();
    v8s af[4], bfr[4];
    #pragma unroll
    for (int mi = 0; mi < 4; ++mi)
      af[mi] = *(const v8s*)(As + ((wm * 64 + mi * 16 + l15) * 32 + l4 * 8) * 2);
    #pragma unroll
    for (int ni = 0; ni < 4; ++ni)
      bfr[ni] = *(const v8s*)(Bs + ((wn * 64 + ni * 16 + l15) * 32 + l4 * 8) * 2);
    #pragma unroll
    for (int mi = 0; mi < 4; ++mi)
      #pragma unroll
      for (int ni = 0; ni < 4; ++ni)
        acc[mi][ni] = __builtin_amdgcn_mfma_f32_16x16x32_bf16(af[mi], bfr[ni], acc[mi][ni], 0, 0, 0);
  }

  if (!F32OUT && n0 >= 1280) {
    // v columns -> Vt[b][g][d][t], 4 contiguous t per lane
    #pragma unroll
    for (int mi = 0; mi < 4; ++mi) {
      #pragma unroll
      for (int ni = 0; ni < 4; ++ni) {
        int col = n0 + wn * 64 + ni * 16 + l15;
        float bv = bias[col];
        int c2 = col - 1280;
        int gg = c2 >> 6, dd = c2 & 63;
        int row = m0 + wm * 64 + mi * 16 + l4 * 4;
        int bb = row >> 11, tt = row & 2047;
        ushort4 ov;
        ov.x = f2bf(acc[mi][ni][0] + bv);
        ov.y = f2bf(acc[mi][ni][1] + bv);
        ov.z = f2bf(acc[mi][ni][2] + bv);
        ov.w = f2bf(acc[mi][ni][3] + bv);
        *(ushort4*)(vtH + ((size_t)((bb * Gn + gg) * 64 + dd)) * Tn + tt) = ov;
      }
    }
  } else if (!F32OUT) {
    // q/k region: fused interleaved RoPE. col parity == lane parity, partner = lane^1.
    #pragma unroll
    for (int mi = 0; mi < 4; ++mi) {
      #pragma unroll
      for (int ni = 0; ni < 4; ++ni) {
        int col = n0 + wn * 64 + ni * 16 + l15;
        float bv = bias[col];
        int d2 = (col & 63) >> 1;
        bool even = !(col & 1);
        #pragma unroll
        for (int r = 0; r < 4; ++r) {
          int row = m0 + wm * 64 + mi * 16 + l4 * 4 + r;
          int tt = row & 2047;
          float2 cs = table[tt * 32 + d2];
          float v = acc[mi][ni][r] + bv;
          float prt = __shfl_xor(v, 1);
          float ov = even ? (v * cs.x - prt * cs.y) : (prt * cs.y + v * cs.x);
          outH[(size_t)row * N + col] = f2bf(ov);
        }
      }
    }
  } else {
    #pragma unroll
    for (int mi = 0; mi < 4; ++mi) {
      #pragma unroll
      for (int ni = 0; ni < 4; ++ni) {
        int col = n0 + wn * 64 + ni * 16 + l15;
        float bv = bias[col];
        #pragma unroll
        for (int r = 0; r < 4; ++r) {
          int row = m0 + wm * 64 + mi * 16 + l4 * 4 + r;
          outF[(size_t)row * N + col] = acc[mi][ni][r] + bv;
        }
      }
    }
  }
}

// ---------------- Flash attention, GQA + sliding window + sink ----------------
// grid (T/128, H, B), 512 thr = 8 waves, wave w owns q rows [qt0+16w, qt0+16w+16).
// Swapped QK^T: S^T = mfma(K,Q); O^T = mfma(V^T, P^T). K and V^T double-buffered
// in LDS via global_load_lds with pre-swizzled source columns.
__global__ __launch_bounds__(512) void k_attn(const unsigned short* __restrict__ qkv,
                                              const unsigned short* __restrict__ vt,
                                              unsigned short* __restrict__ o) {
  __shared__ char smem[2 * 16384];    // per buf: K tile 8KB | V^T tile 8KB
  int qt0 = blockIdx.x * 128;
  int h = blockIdx.y, b = blockIdx.z, g = h >> 2;
  int t = threadIdx.x, lane = t & 63, wave = t >> 6;
  int l15 = lane & 15, l4 = lane >> 4;
  int qw0 = qt0 + wave * 16;

  // tile schedule
  int jt_end = (qt0 + 127) >> 6;
  int wstart = (qt0 > WIN) ? ((qt0 - WIN) >> 6) : 0;
  int nIt = (wstart > 0) ? (jt_end - wstart + 2) : (jt_end + 1);

  // staging source coords (per thread, 1 x 16B per matrix)
  int sr = t >> 3, sc = t & 7;
  int scs = (sc ^ (sr & 7)) << 3;   // pre-swizzled element offset
  const unsigned short* gkb = qkv + (size_t)(b * Tn + sr) * NQKV + 1024 + g * 64 + scs;
  const unsigned short* gvb = vt + ((size_t)((b * Gn + g) * 64 + sr)) * Tn + scs;

  auto stageKV = [&](int buf, int j0) {
    __builtin_amdgcn_global_load_lds((const AS1 void*)(gkb + (size_t)j0 * NQKV),
                                     (AS3 void*)(smem + buf * 16384 + wave * 1024), 16, 0, 0);
    __builtin_amdgcn_global_load_lds((const AS1 void*)(gvb + j0),
                                     (AS3 void*)(smem + buf * 16384 + 8192 + wave * 1024), 16, 0, 0);
  };

  auto jt_of = [&](int it) { return (wstart > 0) ? (it == 0 ? 0 : wstart + it - 1) : it; };

  stageKV(0, jt_of(0) << 6);

  // Q fragments direct from global (post-RoPE, scale pre-folded)
  v8s Qf[2];
  #pragma unroll
  for (int hf = 0; hf < 2; ++hf)
    Qf[hf] = *(const v8s*)(qkv + (size_t)(b * Tn + qw0 + l15) * NQKV + h * 64 + hf * 32 + l4 * 8);

  float m = -INFINITY, lsm = 0.f;
  v4f accO[4] = {};

  __syncthreads();

  for (int it = 0; it < nIt; ++it) {
    int cur = it & 1;
    if (it + 1 < nIt) stageKV(cur ^ 1, jt_of(it + 1) << 6);
    int j0 = jt_of(it) << 6;

    bool skip = (j0 > qw0 + 15) || ((j0 + 63 < qw0 - WIN) && (j0 >= SINKN));
    if (!skip) {
      const char* Kb = smem + cur * 16384;
      const char* Vb = Kb + 8192;
      // S^T[key][q]
      v4f s[4];
      #pragma unroll
      for (int kb = 0; kb < 4; ++kb) {
        int r = kb * 16 + l15;
        v8s kf0 = *(const v8s*)(Kb + r * 128 + ((l4 ^ (r & 7)) << 4));
        v8s kf1 = *(const v8s*)(Kb + r * 128 + (((4 + l4) ^ (r & 7)) << 4));
        v4f z = {};
        z = __builtin_amdgcn_mfma_f32_16x16x32_bf16(kf0, Qf[0], z, 0, 0, 0);
        s[kb] = __builtin_amdgcn_mfma_f32_16x16x32_bf16(kf1, Qf[1], z, 0, 0, 0);
      }
      bool needMask = !((j0 + 63 <= qw0) && (j0 >= qw0 + 15 - WIN));
      if (needMask) {
        #pragma unroll
        for (int kb = 0; kb < 4; ++kb)
          #pragma unroll
          for (int r = 0; r < 4; ++r) {
            int j = j0 + kb * 16 + l4 * 4 + r;
            int qg = qw0 + l15;
            bool valid = (j <= qg) && ((j >= qg - WIN) || (j < SINKN));
            s[kb][r] = valid ? s[kb][r] : -1e30f;
          }
      }
      float mt = -1e30f;
      #pragma unroll
      for (int kb = 0; kb < 4; ++kb)
        #pragma unroll
        for (int r = 0; r < 4; ++r) mt = fmaxf(mt, s[kb][r]);
      mt = fmaxf(mt, __shfl_xor(mt, 16));
      mt = fmaxf(mt, __shfl_xor(mt, 32));
      if (!__all(mt <= m + 8.f)) {      // T13 defer-max
        float mnew = fmaxf(m, mt);
        float alpha = exp2f(m - mnew);  // first tile: exp2(-inf)=0
        lsm *= alpha;
        #pragma unroll
        for (int db = 0; db < 4; ++db) {
          accO[db][0] *= alpha; accO[db][1] *= alpha;
          accO[db][2] *= alpha; accO[db][3] *= alpha;
        }
        m = mnew;
      }
      float lsum = 0.f;
      unsigned pk[4][2];
      #pragma unroll
      for (int kb = 0; kb < 4; ++kb) {
        float p0 = exp2f(s[kb][0] - m);
        float p1 = exp2f(s[kb][1] - m);
        float p2 = exp2f(s[kb][2] - m);
        float p3 = exp2f(s[kb][3] - m);
        lsum += (p0 + p1) + (p2 + p3);
        pk[kb][0] = pack_bf2(p1, p0);
        pk[kb][1] = pack_bf2(p3, p2);
      }
      lsum += __shfl_xor(lsum, 16);
      lsum += __shfl_xor(lsum, 32);
      lsm += lsum;

      // P^T B-frags via shfl, then PV
      int src0 = ((2 * (l4 & 1)) << 4) | l15;
      int src1 = src0 + 16;
      bool hiSel = (l4 >> 1) & 1;
      #pragma unroll
      for (int kc = 0; kc < 2; ++kc) {
        int A0 = __shfl((int)pk[kc * 2][0], src0);
        int A1 = __shfl((int)pk[kc * 2][1], src0);
        int A2 = __shfl((int)pk[kc * 2][0], src1);
        int A3 = __shfl((int)pk[kc * 2][1], src1);
        int B0 = __shfl((int)pk[kc * 2 + 1][0], src0);
        int B1 = __shfl((int)pk[kc * 2 + 1][1], src0);
        int B2 = __shfl((int)pk[kc * 2 + 1][0], src1);
        int B3 = __shfl((int)pk[kc * 2 + 1][1], src1);
        union { int i[4]; v8s v; } u;
        u.i[0] = hiSel ? B0 : A0;
        u.i[1] = hiSel ? B1 : A1;
        u.i[2] = hiSel ? B2 : A2;
        u.i[3] = hiSel ? B3 : A3;
        #pragma unroll
        for (int db = 0; db < 4; ++db) {
          int d = db * 16 + l15;
          v8s vf = *(const v8s*)(Vb + d * 128 + (((kc * 4 + l4) ^ (d & 7)) << 4));
          accO[db] = __builtin_amdgcn_mfma_f32_16x16x32_bf16(vf, u.v, accO[db], 0, 0, 0);
        }
      }
    }
    __syncthreads();
  }

  // normalize + write O[t][h*64+d] bf16
  float inv = 1.f / lsm;
  size_t orow = (size_t)(b * Tn + qw0 + l15) * 1024 + h * 64;
  #pragma unroll
  for (int db = 0; db < 4; ++db) {
    int d0 = db * 16 + l4 * 4;
    ushort4 ov;
    ov.x = f2bf(accO[db][0] * inv);
    ov.y = f2bf(accO[db][1] * inv);
    ov.z = f2bf(accO[db][2] * inv);
    ov.w = f2bf(accO[db][3] * inv);
    *(ushort4*)(o + orow + d0) = ov;
  }
}

extern "C" void kernel_launch(void* const* d_in, const int* in_sizes, int n_in,
                              void* d_out, int out_size, void* d_ws, size_t ws_size,
                              hipStream_t stream) {
  const float* x  = (const float*)d_in[0];
  const float* Wq = (const float*)d_in[1];
  const float* bq = (const float*)d_in[2];
  const float* Wk = (const float*)d_in[3];
  const float* bk = (const float*)d_in[4];
  const float* Wv = (const float*)d_in[5];
  const float* bv = (const float*)d_in[6];
  const float* Wo = (const float*)d_in[7];
  const float* bo = (const float*)d_in[8];
  const int*   pos = (const int*)d_in[9];
  float* out = (float*)d_out;

  char* ws = (char*)d_ws;
  unsigned short* xb      = (unsigned short*)(ws);                        // 8388608 B (reused as attno)
  unsigned short* wt_qkv  = (unsigned short*)(ws + 8388608);              // 3145728 B
  unsigned short* wt_o    = (unsigned short*)(ws + 11534336);             // 2097152 B
  float*          bias_q  = (float*)(ws + 13631488);                      // 6144 B
  float2*         table   = (float2*)(ws + 13637632);                     // 524288 B
  unsigned short* qkvb    = (unsigned short*)(ws + 14161920);             // 12582912 B
  unsigned short* vt      = (unsigned short*)(ws + 26744832);             // 2097152 B
  unsigned short* attno   = xb;                                           // reuse (x bf16 dead after GEMM1)

  // x -> bf16
  k_convert<<<4096, 256, 0, stream>>>(x, xb, 4096 * 1024 / 4);
  // all weight transposes in one launch (SCALE*log2e folded into Wq)
  k_transpose_all<<<dim3(32, 32, 4), dim3(32, 8), 0, stream>>>(Wq, Wk, Wv, Wo, wt_qkv, wt_o);
  // RoPE table + concat bias in one launch
  k_table_bias<<<256, 256, 0, stream>>>(pos, table, bq, bk, bv, bias_q);
  // qkv = x @ [Wq|Wk|Wv] + bias; q,k -> RoPE'd bf16 in qkvb, v -> vt transposed
  k_gemm_bt<false><<<dim3(12, 32), 256, 0, stream>>>(xb, wt_qkv, bias_q, table, nullptr, qkvb, vt,
                                                     4096, NQKV, 1024);
  // attention
  k_attn<<<dim3(16, 16, 2), 512, 0, stream>>>(qkvb, vt, attno);
  // out = attn @ Wo + bo  (f32 out)
  k_gemm_bt<true><<<dim3(8, 32), 256, 0, stream>>>(attno, wt_o, bo, nullptr, out, nullptr, nullptr,
                                                   4096, 1024, 1024);
}

// Round 4
// 102.708 us; speedup vs baseline: 1.2322x; 1.0449x over previous
//
#include <hip/hip_runtime.h>
#include <stdint.h>
#include <math.h>

typedef short v8s __attribute__((ext_vector_type(8)));
typedef float v4f __attribute__((ext_vector_type(4)));

#define DEVI static __device__ __forceinline__
#define AS1 __attribute__((address_space(1)))
#define AS3 __attribute__((address_space(3)))

static constexpr int Bn = 2;
static constexpr int Tn = 2048;
static constexpr int Hn = 16;
static constexpr int Gn = 4;
static constexpr int NQKV = 1536;   // H*D + 2*G*D
static constexpr int WIN = 512;
static constexpr int SINKN = 4;
#define SCALE_L2E (0.125f * 1.4426950408889634f)   // D^-0.5 * log2(e), folded into Wq/bq

DEVI unsigned short f2bf(float f) {
  unsigned u = __float_as_uint(f);
  u += 0x7fffu + ((u >> 16) & 1u);
  return (unsigned short)(u >> 16);
}
DEVI float bf2f(unsigned short h) { return __uint_as_float(((unsigned)h) << 16); }
// pack two f32 -> bf16x2 by truncation: low short = lo, high short = hi
DEVI unsigned pack_bf2(float hi, float lo) {
  return __builtin_amdgcn_perm(__float_as_uint(hi), __float_as_uint(lo), 0x07060302u);
}

// ---------------- fp32 -> bf16 convert (4 elems/thread) ----------------
__global__ __launch_bounds__(256) void k_convert(const float* __restrict__ in,
                                                 unsigned short* __restrict__ out, int n4) {
  int i = blockIdx.x * 256 + threadIdx.x;
  if (i >= n4) return;
  float4 v = ((const float4*)in)[i];
  ushort4 o;
  o.x = f2bf(v.x); o.y = f2bf(v.y); o.z = f2bf(v.z); o.w = f2bf(v.w);
  ((ushort4*)out)[i] = o;
}

// ------------- all four W[K][N] f32 -> Wt[N][K] bf16 * scale + table/bias, one launch -------------
// z: 0=Wq(scale) 1=Wk 2=Wv 3=Wo 4=rope-table+bias-concat
__global__ __launch_bounds__(256) void k_transpose_all(const float* __restrict__ Wq,
                                                       const float* __restrict__ Wk,
                                                       const float* __restrict__ Wv,
                                                       const float* __restrict__ Wo,
                                                       unsigned short* __restrict__ wt_qkv,
                                                       unsigned short* __restrict__ wt_o,
                                                       const int* __restrict__ posp,
                                                       float2* __restrict__ table,
                                                       const float* __restrict__ bq,
                                                       const float* __restrict__ bk,
                                                       const float* __restrict__ bv,
                                                       float* __restrict__ biasout) {
  int z = blockIdx.z;
  int tx = threadIdx.x, ty = threadIdx.y;   // block (32,8)
  if (z == 4) {
    int i = (blockIdx.y * 32 + blockIdx.x) * 256 + ty * 32 + tx;
    if (i < Tn * 32) {
      int t = i >> 5, d2 = i & 31;
      float inv = powf(10000.f, -(float)d2 / 32.f);
      float theta = (float)(posp[0] + t) * inv;
      float s, c;
      sincosf(theta, &s, &c);
      table[i] = make_float2(c, s);
    }
    if (i < NQKV)
      biasout[i] = (i < 1024) ? bq[i] * SCALE_L2E : (i < 1280 ? bk[i - 1024] : bv[i - 1280]);
    return;
  }
  const float* W; unsigned short* Wt; int N; float scale = 1.f;
  if (z == 0)      { W = Wq; Wt = wt_qkv;                 N = 1024; scale = SCALE_L2E; }
  else if (z == 1) { W = Wk; Wt = wt_qkv + 1024 * 1024;   N = 256; }
  else if (z == 2) { W = Wv; Wt = wt_qkv + 1280 * 1024;   N = 256; }
  else             { W = Wo; Wt = wt_o;                   N = 1024; }
  int n0 = blockIdx.x * 32, k0 = blockIdx.y * 32;
  if (n0 >= N) return;
  __shared__ float tile[32][33];
  #pragma unroll
  for (int yy = 0; yy < 4; ++yy)
    tile[ty + yy * 8][tx] = W[(size_t)(k0 + ty + yy * 8) * N + n0 + tx];
  __syncthreads();
  #pragma unroll
  for (int yy = 0; yy < 4; ++yy)
    Wt[(size_t)(n0 + ty + yy * 8) * 1024 + k0 + tx] = f2bf(tile[tx][ty + yy * 8] * scale);
}

// ---------------- GEMM: C[M][N] = A[M][K](bf16) * Bt[N][K]^T + bias ----------------
// 128x128 tile, BK=64, 4 waves (2x2), single-buffer 2-barrier per 64-wide K-step.
// XCD-aware tile swizzle (nwg % 8 == 0 required).
// F32OUT=false: n0<1280 -> RoPE applied (interleaved pairs via shfl_xor(1)), bf16 row-major;
//               n0>=1280 -> v cols transposed to vtH[b][g][d][t].
template <bool F32OUT>
__global__ __launch_bounds__(256) void k_gemm_bt(const unsigned short* __restrict__ A,
                                                 const unsigned short* __restrict__ Bt,
                                                 const float* __restrict__ bias,
                                                 const float2* __restrict__ table,
                                                 float* __restrict__ outF,
                                                 unsigned short* __restrict__ outH,
                                                 unsigned short* __restrict__ vtH,
                                                 int M, int N, int K) {
  __shared__ char As[16384];    // [128 rows][128 B] (64 bf16)
  __shared__ char Bs[16384];
  // XCD swizzle: dispatch id -> contiguous tile range per XCD (same m-panel grouped)
  int nx = gridDim.x;
  int nwg = nx * gridDim.y;
  int id = blockIdx.y * nx + blockIdx.x;
  int swz = (id & 7) * (nwg >> 3) + (id >> 3);
  int m0 = (swz / nx) * 128, n0 = (swz % nx) * 128;

  int t = threadIdx.x, lane = t & 63, wave = t >> 6;
  int wm = wave >> 1, wn = wave & 1;
  int l15 = lane & 15, l4 = lane >> 4;
  v4f acc[4][4] = {};

  for (int k0 = 0; k0 < K; k0 += 64) {
    __syncthreads();
    #pragma unroll
    for (int p = 0; p < 4; ++p) {
      int cid = p * 256 + t;
      int row = cid >> 3, cc = cid & 7;
      const unsigned short* ga = A + (size_t)(m0 + row) * K + k0 + cc * 8;
      const unsigned short* gb = Bt + (size_t)(n0 + row) * K + k0 + cc * 8;
      __builtin_amdgcn_global_load_lds((const AS1 void*)ga,
                                       (AS3 void*)(As + p * 4096 + wave * 1024), 16, 0, 0);
      __builtin_amdgcn_global_load_lds((const AS1 void*)gb,
                                       (AS3 void*)(Bs + p * 4096 + wave * 1024), 16, 0, 0);
    }
    __syncthreads();
    #pragma unroll
    for (int kk = 0; kk < 2; ++kk) {
      v8s af[4], bfr[4];
      #pragma unroll
      for (int mi = 0; mi < 4; ++mi)
        af[mi] = *(const v8s*)(As + (wm * 64 + mi * 16 + l15) * 128 + kk * 64 + l4 * 16);
      #pragma unroll
      for (int ni = 0; ni < 4; ++ni)
        bfr[ni] = *(const v8s*)(Bs + (wn * 64 + ni * 16 + l15) * 128 + kk * 64 + l4 * 16);
      #pragma unroll
      for (int mi = 0; mi < 4; ++mi)
        #pragma unroll
        for (int ni = 0; ni < 4; ++ni)
          acc[mi][ni] = __builtin_amdgcn_mfma_f32_16x16x32_bf16(af[mi], bfr[ni], acc[mi][ni], 0, 0, 0);
    }
  }

  if (!F32OUT && n0 >= 1280) {
    // v columns -> Vt[b][g][d][t], 4 contiguous t per lane
    #pragma unroll
    for (int mi = 0; mi < 4; ++mi) {
      #pragma unroll
      for (int ni = 0; ni < 4; ++ni) {
        int col = n0 + wn * 64 + ni * 16 + l15;
        float bv = bias[col];
        int c2 = col - 1280;
        int gg = c2 >> 6, dd = c2 & 63;
        int row = m0 + wm * 64 + mi * 16 + l4 * 4;
        int bb = row >> 11, tt = row & 2047;
        ushort4 ov;
        ov.x = f2bf(acc[mi][ni][0] + bv);
        ov.y = f2bf(acc[mi][ni][1] + bv);
        ov.z = f2bf(acc[mi][ni][2] + bv);
        ov.w = f2bf(acc[mi][ni][3] + bv);
        *(ushort4*)(vtH + ((size_t)((bb * Gn + gg) * 64 + dd)) * Tn + tt) = ov;
      }
    }
  } else if (!F32OUT) {
    // q/k region: fused interleaved RoPE. col parity == lane parity, partner = lane^1.
    #pragma unroll
    for (int mi = 0; mi < 4; ++mi) {
      #pragma unroll
      for (int ni = 0; ni < 4; ++ni) {
        int col = n0 + wn * 64 + ni * 16 + l15;
        float bv = bias[col];
        int d2 = (col & 63) >> 1;
        bool even = !(col & 1);
        #pragma unroll
        for (int r = 0; r < 4; ++r) {
          int row = m0 + wm * 64 + mi * 16 + l4 * 4 + r;
          int tt = row & 2047;
          float2 cs = table[tt * 32 + d2];
          float v = acc[mi][ni][r] + bv;
          float prt = __shfl_xor(v, 1);
          float ov = even ? (v * cs.x - prt * cs.y) : (prt * cs.y + v * cs.x);
          outH[(size_t)row * N + col] = f2bf(ov);
        }
      }
    }
  } else {
    #pragma unroll
    for (int mi = 0; mi < 4; ++mi) {
      #pragma unroll
      for (int ni = 0; ni < 4; ++ni) {
        int col = n0 + wn * 64 + ni * 16 + l15;
        float bv = bias[col];
        #pragma unroll
        for (int r = 0; r < 4; ++r) {
          int row = m0 + wm * 64 + mi * 16 + l4 * 4 + r;
          outF[(size_t)row * N + col] = acc[mi][ni][r] + bv;
        }
      }
    }
  }
}

// ---------------- Flash attention, GQA + sliding window + sink ----------------
// grid (T/128, H, B), 512 thr = 8 waves, wave w owns q rows [qt0+16w, qt0+16w+16).
// Swapped QK^T: S^T = mfma(K,Q); O^T = mfma(V^T, P^T). K and V^T double-buffered
// in LDS via global_load_lds with pre-swizzled source columns.
__global__ __launch_bounds__(512) void k_attn(const unsigned short* __restrict__ qkv,
                                              const unsigned short* __restrict__ vt,
                                              unsigned short* __restrict__ o) {
  __shared__ char smem[2 * 16384];    // per buf: K tile 8KB | V^T tile 8KB
  int qt0 = blockIdx.x * 128;
  int h = blockIdx.y, b = blockIdx.z, g = h >> 2;
  int t = threadIdx.x, lane = t & 63, wave = t >> 6;
  int l15 = lane & 15, l4 = lane >> 4;
  int qw0 = qt0 + wave * 16;

  // tile schedule
  int jt_end = (qt0 + 127) >> 6;
  int wstart = (qt0 > WIN) ? ((qt0 - WIN) >> 6) : 0;
  int nIt = (wstart > 0) ? (jt_end - wstart + 2) : (jt_end + 1);

  // staging source coords (per thread, 1 x 16B per matrix)
  int sr = t >> 3, sc = t & 7;
  int scs = (sc ^ (sr & 7)) << 3;   // pre-swizzled element offset
  const unsigned short* gkb = qkv + (size_t)(b * Tn + sr) * NQKV + 1024 + g * 64 + scs;
  const unsigned short* gvb = vt + ((size_t)((b * Gn + g) * 64 + sr)) * Tn + scs;

  auto stageKV = [&](int buf, int j0) {
    __builtin_amdgcn_global_load_lds((const AS1 void*)(gkb + (size_t)j0 * NQKV),
                                     (AS3 void*)(smem + buf * 16384 + wave * 1024), 16, 0, 0);
    __builtin_amdgcn_global_load_lds((const AS1 void*)(gvb + j0),
                                     (AS3 void*)(smem + buf * 16384 + 8192 + wave * 1024), 16, 0, 0);
  };

  auto jt_of = [&](int it) { return (wstart > 0) ? (it == 0 ? 0 : wstart + it - 1) : it; };

  stageKV(0, jt_of(0) << 6);

  // Q fragments direct from global (post-RoPE, scale pre-folded)
  v8s Qf[2];
  #pragma unroll
  for (int hf = 0; hf < 2; ++hf)
    Qf[hf] = *(const v8s*)(qkv + (size_t)(b * Tn + qw0 + l15) * NQKV + h * 64 + hf * 32 + l4 * 8);

  float m = -INFINITY, lsm = 0.f;
  v4f accO[4] = {};

  __syncthreads();

  for (int it = 0; it < nIt; ++it) {
    int cur = it & 1;
    if (it + 1 < nIt) stageKV(cur ^ 1, jt_of(it + 1) << 6);
    int j0 = jt_of(it) << 6;

    bool skip = (j0 > qw0 + 15) || ((j0 + 63 < qw0 - WIN) && (j0 >= SINKN));
    if (!skip) {
      const char* Kb = smem + cur * 16384;
      const char* Vb = Kb + 8192;
      // S^T[key][q]
      v4f s[4];
      #pragma unroll
      for (int kb = 0; kb < 4; ++kb) {
        int r = kb * 16 + l15;
        v8s kf0 = *(const v8s*)(Kb + r * 128 + ((l4 ^ (r & 7)) << 4));
        v8s kf1 = *(const v8s*)(Kb + r * 128 + (((4 + l4) ^ (r & 7)) << 4));
        v4f z = {};
        z = __builtin_amdgcn_mfma_f32_16x16x32_bf16(kf0, Qf[0], z, 0, 0, 0);
        s[kb] = __builtin_amdgcn_mfma_f32_16x16x32_bf16(kf1, Qf[1], z, 0, 0, 0);
      }
      bool needMask = !((j0 + 63 <= qw0) && (j0 >= qw0 + 15 - WIN));
      if (needMask) {
        #pragma unroll
        for (int kb = 0; kb < 4; ++kb)
          #pragma unroll
          for (int r = 0; r < 4; ++r) {
            int j = j0 + kb * 16 + l4 * 4 + r;
            int qg = qw0 + l15;
            bool valid = (j <= qg) && ((j >= qg - WIN) || (j < SINKN));
            s[kb][r] = valid ? s[kb][r] : -1e30f;
          }
      }
      float mt = -1e30f;
      #pragma unroll
      for (int kb = 0; kb < 4; ++kb)
        #pragma unroll
        for (int r = 0; r < 4; ++r) mt = fmaxf(mt, s[kb][r]);
      mt = fmaxf(mt, __shfl_xor(mt, 16));
      mt = fmaxf(mt, __shfl_xor(mt, 32));
      if (!__all(mt <= m + 8.f)) {      // T13 defer-max
        float mnew = fmaxf(m, mt);
        float alpha = exp2f(m - mnew);  // first tile: exp2(-inf)=0
        lsm *= alpha;
        #pragma unroll
        for (int db = 0; db < 4; ++db) {
          accO[db][0] *= alpha; accO[db][1] *= alpha;
          accO[db][2] *= alpha; accO[db][3] *= alpha;
        }
        m = mnew;
      }
      float lsum = 0.f;
      unsigned pk[4][2];
      #pragma unroll
      for (int kb = 0; kb < 4; ++kb) {
        float p0 = exp2f(s[kb][0] - m);
        float p1 = exp2f(s[kb][1] - m);
        float p2 = exp2f(s[kb][2] - m);
        float p3 = exp2f(s[kb][3] - m);
        lsum += (p0 + p1) + (p2 + p3);
        pk[kb][0] = pack_bf2(p1, p0);
        pk[kb][1] = pack_bf2(p3, p2);
      }
      lsum += __shfl_xor(lsum, 16);
      lsum += __shfl_xor(lsum, 32);
      lsm += lsum;

      // P^T B-frags via shfl, then PV
      int src0 = ((2 * (l4 & 1)) << 4) | l15;
      int src1 = src0 + 16;
      bool hiSel = (l4 >> 1) & 1;
      #pragma unroll
      for (int kc = 0; kc < 2; ++kc) {
        int A0 = __shfl((int)pk[kc * 2][0], src0);
        int A1 = __shfl((int)pk[kc * 2][1], src0);
        int A2 = __shfl((int)pk[kc * 2][0], src1);
        int A3 = __shfl((int)pk[kc * 2][1], src1);
        int B0 = __shfl((int)pk[kc * 2 + 1][0], src0);
        int B1 = __shfl((int)pk[kc * 2 + 1][1], src0);
        int B2 = __shfl((int)pk[kc * 2 + 1][0], src1);
        int B3 = __shfl((int)pk[kc * 2 + 1][1], src1);
        union { int i[4]; v8s v; } u;
        u.i[0] = hiSel ? B0 : A0;
        u.i[1] = hiSel ? B1 : A1;
        u.i[2] = hiSel ? B2 : A2;
        u.i[3] = hiSel ? B3 : A3;
        #pragma unroll
        for (int db = 0; db < 4; ++db) {
          int d = db * 16 + l15;
          v8s vf = *(const v8s*)(Vb + d * 128 + (((kc * 4 + l4) ^ (d & 7)) << 4));
          accO[db] = __builtin_amdgcn_mfma_f32_16x16x32_bf16(vf, u.v, accO[db], 0, 0, 0);
        }
      }
    }
    __syncthreads();
  }

  // normalize + write O[t][h*64+d] bf16
  float inv = 1.f / lsm;
  size_t orow = (size_t)(b * Tn + qw0 + l15) * 1024 + h * 64;
  #pragma unroll
  for (int db = 0; db < 4; ++db) {
    int d0 = db * 16 + l4 * 4;
    ushort4 ov;
    ov.x = f2bf(accO[db][0] * inv);
    ov.y = f2bf(accO[db][1] * inv);
    ov.z = f2bf(accO[db][2] * inv);
    ov.w = f2bf(accO[db][3] * inv);
    *(ushort4*)(o + orow + d0) = ov;
  }
}

extern "C" void kernel_launch(void* const* d_in, const int* in_sizes, int n_in,
                              void* d_out, int out_size, void* d_ws, size_t ws_size,
                              hipStream_t stream) {
  const float* x  = (const float*)d_in[0];
  const float* Wq = (const float*)d_in[1];
  const float* bq = (const float*)d_in[2];
  const float* Wk = (const float*)d_in[3];
  const float* bk = (const float*)d_in[4];
  const float* Wv = (const float*)d_in[5];
  const float* bv = (const float*)d_in[6];
  const float* Wo = (const float*)d_in[7];
  const float* bo = (const float*)d_in[8];
  const int*   pos = (const int*)d_in[9];
  float* out = (float*)d_out;

  char* ws = (char*)d_ws;
  unsigned short* xb      = (unsigned short*)(ws);                        // 8388608 B (reused as attno)
  unsigned short* wt_qkv  = (unsigned short*)(ws + 8388608);              // 3145728 B
  unsigned short* wt_o    = (unsigned short*)(ws + 11534336);             // 2097152 B
  float*          bias_q  = (float*)(ws + 13631488);                      // 6144 B
  float2*         table   = (float2*)(ws + 13637632);                     // 524288 B
  unsigned short* qkvb    = (unsigned short*)(ws + 14161920);             // 12582912 B
  unsigned short* vt      = (unsigned short*)(ws + 26744832);             // 2097152 B
  unsigned short* attno   = xb;                                           // reuse (x bf16 dead after GEMM1)

  // x -> bf16
  k_convert<<<4096, 256, 0, stream>>>(x, xb, 4096 * 1024 / 4);
  // all weight transposes + rope table + bias concat in one launch
  k_transpose_all<<<dim3(32, 32, 5), dim3(32, 8), 0, stream>>>(Wq, Wk, Wv, Wo, wt_qkv, wt_o,
                                                               pos, table, bq, bk, bv, bias_q);
  // qkv = x @ [Wq|Wk|Wv] + bias; q,k -> RoPE'd bf16 in qkvb, v -> vt transposed
  k_gemm_bt<false><<<dim3(12, 32), 256, 0, stream>>>(xb, wt_qkv, bias_q, table, nullptr, qkvb, vt,
                                                     4096, NQKV, 1024);
  // attention
  k_attn<<<dim3(16, 16, 2), 512, 0, stream>>>(qkvb, vt, attno);
  // out = attn @ Wo + bo  (f32 out)
  k_gemm_bt<true><<<dim3(8, 32), 256, 0, stream>>>(attno, wt_o, bo, nullptr, out, nullptr, nullptr,
                                                   4096, 1024, 1024);
}

// Round 5
// 90.332 us; speedup vs baseline: 1.4011x; 1.1370x over previous
//
#include <hip/hip_runtime.h>
#include <stdint.h>
#include <math.h>

typedef short v8s __attribute__((ext_vector_type(8)));
typedef float v4f __attribute__((ext_vector_type(4)));

#define DEVI static __device__ __forceinline__
#define AS1 __attribute__((address_space(1)))
#define AS3 __attribute__((address_space(3)))

static constexpr int Bn = 2;
static constexpr int Tn = 2048;
static constexpr int Hn = 16;
static constexpr int Gn = 4;
static constexpr int NQKV = 1536;   // H*D + 2*G*D
static constexpr int WIN = 512;
static constexpr int SINKN = 4;
#define SCALE_L2E (0.125f * 1.4426950408889634f)   // D^-0.5 * log2(e), folded into Wq/bq

DEVI unsigned short f2bf(float f) {
  unsigned u = __float_as_uint(f);
  u += 0x7fffu + ((u >> 16) & 1u);
  return (unsigned short)(u >> 16);
}
DEVI float bf2f(unsigned short h) { return __uint_as_float(((unsigned)h) << 16); }
// pack two f32 -> bf16x2 by truncation: low short = lo, high short = hi
DEVI unsigned pack_bf2(float hi, float lo) {
  return __builtin_amdgcn_perm(__float_as_uint(hi), __float_as_uint(lo), 0x07060302u);
}

// ------------- weights transpose + rope table + bias + x-convert, one launch -------------
// z: 0=Wq(scale) 1=Wk 2=Wv 3=Wo 4=rope-table+bias-concat 5=x fp32->bf16
__global__ __launch_bounds__(256) void k_transpose_all(const float* __restrict__ Wq,
                                                       const float* __restrict__ Wk,
                                                       const float* __restrict__ Wv,
                                                       const float* __restrict__ Wo,
                                                       unsigned short* __restrict__ wt_qkv,
                                                       unsigned short* __restrict__ wt_o,
                                                       const int* __restrict__ posp,
                                                       float2* __restrict__ table,
                                                       const float* __restrict__ bq,
                                                       const float* __restrict__ bk,
                                                       const float* __restrict__ bv,
                                                       float* __restrict__ biasout,
                                                       const float* __restrict__ x,
                                                       unsigned short* __restrict__ xb) {
  int z = blockIdx.z;
  int tx = threadIdx.x, ty = threadIdx.y;   // block (32,8)
  if (z == 5) {
    // x -> bf16, 4 float4 per thread (1024 blocks * 256 thr * 4 = 1,048,576 float4)
    int base = (blockIdx.y * 32 + blockIdx.x) * 256 + ty * 32 + tx;
    #pragma unroll
    for (int j = 0; j < 4; ++j) {
      int i = base + j * 262144;
      float4 v = ((const float4*)x)[i];
      ushort4 o;
      o.x = f2bf(v.x); o.y = f2bf(v.y); o.z = f2bf(v.z); o.w = f2bf(v.w);
      ((ushort4*)xb)[i] = o;
    }
    return;
  }
  if (z == 4) {
    int i = (blockIdx.y * 32 + blockIdx.x) * 256 + ty * 32 + tx;
    if (i < Tn * 32) {
      int t = i >> 5, d2 = i & 31;
      float inv = powf(10000.f, -(float)d2 / 32.f);
      float theta = (float)(posp[0] + t) * inv;
      float s, c;
      sincosf(theta, &s, &c);
      table[i] = make_float2(c, s);
    }
    if (i < NQKV)
      biasout[i] = (i < 1024) ? bq[i] * SCALE_L2E : (i < 1280 ? bk[i - 1024] : bv[i - 1280]);
    return;
  }
  const float* W; unsigned short* Wt; int N; float scale = 1.f;
  if (z == 0)      { W = Wq; Wt = wt_qkv;                 N = 1024; scale = SCALE_L2E; }
  else if (z == 1) { W = Wk; Wt = wt_qkv + 1024 * 1024;   N = 256; }
  else if (z == 2) { W = Wv; Wt = wt_qkv + 1280 * 1024;   N = 256; }
  else             { W = Wo; Wt = wt_o;                   N = 1024; }
  int n0 = blockIdx.x * 32, k0 = blockIdx.y * 32;
  if (n0 >= N) return;
  __shared__ float tile[32][33];
  #pragma unroll
  for (int yy = 0; yy < 4; ++yy)
    tile[ty + yy * 8][tx] = W[(size_t)(k0 + ty + yy * 8) * N + n0 + tx];
  __syncthreads();
  #pragma unroll
  for (int yy = 0; yy < 4; ++yy)
    Wt[(size_t)(n0 + ty + yy * 8) * 1024 + k0 + tx] = f2bf(tile[tx][ty + yy * 8] * scale);
}

// ---------------- GEMM: C[M][N] = A[M][K](bf16) * Bt[N][K]^T + bias ----------------
// 64x128 tile, BK=64, 4 waves (2 wm x 2 wn), single-buffer 2-barrier per K-step.
// Grid (N/128, M/64) -> GEMM1 768 blocks (3/CU), GEMM2 512 (2/CU): balanced + overlap.
// XCD-aware tile swizzle (nwg % 8 == 0 required).
// F32OUT=false: n0<1280 -> RoPE applied (interleaved pairs via shfl_xor(1)), bf16 row-major;
//               n0>=1280 -> v cols transposed to vtH[b][g][d][t].
template <bool F32OUT>
__global__ __launch_bounds__(256) void k_gemm_bt(const unsigned short* __restrict__ A,
                                                 const unsigned short* __restrict__ Bt,
                                                 const float* __restrict__ bias,
                                                 const float2* __restrict__ table,
                                                 float* __restrict__ outF,
                                                 unsigned short* __restrict__ outH,
                                                 unsigned short* __restrict__ vtH,
                                                 int M, int N, int K) {
  __shared__ char As[8192];     // [64 rows][128 B] (64 bf16)
  __shared__ char Bs[16384];    // [128 rows][128 B]
  int nx = gridDim.x;
  int nwg = nx * gridDim.y;
  int id = blockIdx.y * nx + blockIdx.x;
  int swz = (id & 7) * (nwg >> 3) + (id >> 3);
  int m0 = (swz / nx) * 64, n0 = (swz % nx) * 128;

  int t = threadIdx.x, lane = t & 63, wave = t >> 6;
  int wm = wave >> 1, wn = wave & 1;
  int l15 = lane & 15, l4 = lane >> 4;
  v4f acc[2][4] = {};

  for (int k0 = 0; k0 < K; k0 += 64) {
    __syncthreads();
    #pragma unroll
    for (int p = 0; p < 2; ++p) {     // A: 512 chunks of 16B
      int cid = p * 256 + t;
      int row = cid >> 3, cc = cid & 7;
      const unsigned short* ga = A + (size_t)(m0 + row) * K + k0 + cc * 8;
      __builtin_amdgcn_global_load_lds((const AS1 void*)ga,
                                       (AS3 void*)(As + p * 4096 + wave * 1024), 16, 0, 0);
    }
    #pragma unroll
    for (int p = 0; p < 4; ++p) {     // B: 1024 chunks of 16B
      int cid = p * 256 + t;
      int row = cid >> 3, cc = cid & 7;
      const unsigned short* gb = Bt + (size_t)(n0 + row) * K + k0 + cc * 8;
      __builtin_amdgcn_global_load_lds((const AS1 void*)gb,
                                       (AS3 void*)(Bs + p * 4096 + wave * 1024), 16, 0, 0);
    }
    __syncthreads();
    #pragma unroll
    for (int kk = 0; kk < 2; ++kk) {
      v8s af[2], bfr[4];
      #pragma unroll
      for (int mi = 0; mi < 2; ++mi)
        af[mi] = *(const v8s*)(As + (wm * 32 + mi * 16 + l15) * 128 + kk * 64 + l4 * 16);
      #pragma unroll
      for (int ni = 0; ni < 4; ++ni)
        bfr[ni] = *(const v8s*)(Bs + (wn * 64 + ni * 16 + l15) * 128 + kk * 64 + l4 * 16);
      #pragma unroll
      for (int mi = 0; mi < 2; ++mi)
        #pragma unroll
        for (int ni = 0; ni < 4; ++ni)
          acc[mi][ni] = __builtin_amdgcn_mfma_f32_16x16x32_bf16(af[mi], bfr[ni], acc[mi][ni], 0, 0, 0);
    }
  }

  if (!F32OUT && n0 >= 1280) {
    // v columns -> Vt[b][g][d][t], 4 contiguous t per lane
    #pragma unroll
    for (int mi = 0; mi < 2; ++mi) {
      #pragma unroll
      for (int ni = 0; ni < 4; ++ni) {
        int col = n0 + wn * 64 + ni * 16 + l15;
        float bv = bias[col];
        int c2 = col - 1280;
        int gg = c2 >> 6, dd = c2 & 63;
        int row = m0 + wm * 32 + mi * 16 + l4 * 4;
        int bb = row >> 11, tt = row & 2047;
        ushort4 ov;
        ov.x = f2bf(acc[mi][ni][0] + bv);
        ov.y = f2bf(acc[mi][ni][1] + bv);
        ov.z = f2bf(acc[mi][ni][2] + bv);
        ov.w = f2bf(acc[mi][ni][3] + bv);
        *(ushort4*)(vtH + ((size_t)((bb * Gn + gg) * 64 + dd)) * Tn + tt) = ov;
      }
    }
  } else if (!F32OUT) {
    // q/k region: fused interleaved RoPE. col parity == lane parity, partner = lane^1.
    #pragma unroll
    for (int mi = 0; mi < 2; ++mi) {
      #pragma unroll
      for (int ni = 0; ni < 4; ++ni) {
        int col = n0 + wn * 64 + ni * 16 + l15;
        float bv = bias[col];
        int d2 = (col & 63) >> 1;
        bool even = !(col & 1);
        #pragma unroll
        for (int r = 0; r < 4; ++r) {
          int row = m0 + wm * 32 + mi * 16 + l4 * 4 + r;
          int tt = row & 2047;
          float2 cs = table[tt * 32 + d2];
          float v = acc[mi][ni][r] + bv;
          float prt = __shfl_xor(v, 1);
          float ov = even ? (v * cs.x - prt * cs.y) : (prt * cs.y + v * cs.x);
          outH[(size_t)row * N + col] = f2bf(ov);
        }
      }
    }
  } else {
    #pragma unroll
    for (int mi = 0; mi < 2; ++mi) {
      #pragma unroll
      for (int ni = 0; ni < 4; ++ni) {
        int col = n0 + wn * 64 + ni * 16 + l15;
        float bv = bias[col];
        #pragma unroll
        for (int r = 0; r < 4; ++r) {
          int row = m0 + wm * 32 + mi * 16 + l4 * 4 + r;
          outF[(size_t)row * N + col] = acc[mi][ni][r] + bv;
        }
      }
    }
  }
}

// ---------------- Flash attention, GQA + sliding window + sink ----------------
// 1D grid of 512 blocks, 512 thr = 8 waves, wave w owns q rows [qt0+16w, qt0+16w+16).
// Load-balance pairing: block i and i+256 land on the same CU; b=1 half gets the
// reversed q-tile index so per-CU work is ~constant.
// Swapped QK^T: S^T = mfma(K,Q); O^T = mfma(V^T, P^T). K and V^T double-buffered
// in LDS via global_load_lds with pre-swizzled source columns.
__global__ __launch_bounds__(512) void k_attn(const unsigned short* __restrict__ qkv,
                                              const unsigned short* __restrict__ vt,
                                              unsigned short* __restrict__ o) {
  __shared__ char smem[2 * 16384];    // per buf: K tile 8KB | V^T tile 8KB
  int id = blockIdx.x;
  int half = id >> 8, r5 = id & 255;
  int h = r5 >> 4;
  int qtile = half ? (15 - (r5 & 15)) : (r5 & 15);
  int b = half;
  int qt0 = qtile * 128;
  int g = h >> 2;
  int t = threadIdx.x, lane = t & 63, wave = t >> 6;
  int l15 = lane & 15, l4 = lane >> 4;
  int qw0 = qt0 + wave * 16;

  // tile schedule
  int jt_end = (qt0 + 127) >> 6;
  int wstart = (qt0 > WIN) ? ((qt0 - WIN) >> 6) : 0;
  int nIt = (wstart > 0) ? (jt_end - wstart + 2) : (jt_end + 1);

  // staging source coords (per thread, 1 x 16B per matrix)
  int sr = t >> 3, sc = t & 7;
  int scs = (sc ^ (sr & 7)) << 3;   // pre-swizzled element offset
  const unsigned short* gkb = qkv + (size_t)(b * Tn + sr) * NQKV + 1024 + g * 64 + scs;
  const unsigned short* gvb = vt + ((size_t)((b * Gn + g) * 64 + sr)) * Tn + scs;

  auto stageKV = [&](int buf, int j0) {
    __builtin_amdgcn_global_load_lds((const AS1 void*)(gkb + (size_t)j0 * NQKV),
                                     (AS3 void*)(smem + buf * 16384 + wave * 1024), 16, 0, 0);
    __builtin_amdgcn_global_load_lds((const AS1 void*)(gvb + j0),
                                     (AS3 void*)(smem + buf * 16384 + 8192 + wave * 1024), 16, 0, 0);
  };

  auto jt_of = [&](int it) { return (wstart > 0) ? (it == 0 ? 0 : wstart + it - 1) : it; };

  stageKV(0, jt_of(0) << 6);

  // Q fragments direct from global (post-RoPE, scale pre-folded)
  v8s Qf[2];
  #pragma unroll
  for (int hf = 0; hf < 2; ++hf)
    Qf[hf] = *(const v8s*)(qkv + (size_t)(b * Tn + qw0 + l15) * NQKV + h * 64 + hf * 32 + l4 * 8);

  float m = -INFINITY, lsm = 0.f;
  v4f accO[4] = {};

  __syncthreads();

  for (int it = 0; it < nIt; ++it) {
    int cur = it & 1;
    if (it + 1 < nIt) stageKV(cur ^ 1, jt_of(it + 1) << 6);
    int j0 = jt_of(it) << 6;

    bool skip = (j0 > qw0 + 15) || ((j0 + 63 < qw0 - WIN) && (j0 >= SINKN));
    if (!skip) {
      const char* Kb = smem + cur * 16384;
      const char* Vb = Kb + 8192;
      // S^T[key][q]
      v4f s[4];
      #pragma unroll
      for (int kb = 0; kb < 4; ++kb) {
        int r = kb * 16 + l15;
        v8s kf0 = *(const v8s*)(Kb + r * 128 + ((l4 ^ (r & 7)) << 4));
        v8s kf1 = *(const v8s*)(Kb + r * 128 + (((4 + l4) ^ (r & 7)) << 4));
        v4f z = {};
        z = __builtin_amdgcn_mfma_f32_16x16x32_bf16(kf0, Qf[0], z, 0, 0, 0);
        s[kb] = __builtin_amdgcn_mfma_f32_16x16x32_bf16(kf1, Qf[1], z, 0, 0, 0);
      }
      bool needMask = !((j0 + 63 <= qw0) && (j0 >= qw0 + 15 - WIN));
      if (needMask) {
        #pragma unroll
        for (int kb = 0; kb < 4; ++kb)
          #pragma unroll
          for (int r = 0; r < 4; ++r) {
            int j = j0 + kb * 16 + l4 * 4 + r;
            int qg = qw0 + l15;
            bool valid = (j <= qg) && ((j >= qg - WIN) || (j < SINKN));
            s[kb][r] = valid ? s[kb][r] : -1e30f;
          }
      }
      float mt = -1e30f;
      #pragma unroll
      for (int kb = 0; kb < 4; ++kb)
        #pragma unroll
        for (int r = 0; r < 4; ++r) mt = fmaxf(mt, s[kb][r]);
      mt = fmaxf(mt, __shfl_xor(mt, 16));
      mt = fmaxf(mt, __shfl_xor(mt, 32));
      if (!__all(mt <= m + 8.f)) {      // T13 defer-max
        float mnew = fmaxf(m, mt);
        float alpha = exp2f(m - mnew);  // first tile: exp2(-inf)=0
        lsm *= alpha;
        #pragma unroll
        for (int db = 0; db < 4; ++db) {
          accO[db][0] *= alpha; accO[db][1] *= alpha;
          accO[db][2] *= alpha; accO[db][3] *= alpha;
        }
        m = mnew;
      }
      float lsum = 0.f;
      unsigned pk[4][2];
      #pragma unroll
      for (int kb = 0; kb < 4; ++kb) {
        float p0 = exp2f(s[kb][0] - m);
        float p1 = exp2f(s[kb][1] - m);
        float p2 = exp2f(s[kb][2] - m);
        float p3 = exp2f(s[kb][3] - m);
        lsum += (p0 + p1) + (p2 + p3);
        pk[kb][0] = pack_bf2(p1, p0);
        pk[kb][1] = pack_bf2(p3, p2);
      }
      lsum += __shfl_xor(lsum, 16);
      lsum += __shfl_xor(lsum, 32);
      lsm += lsum;

      // P^T B-frags via shfl, then PV
      int src0 = ((2 * (l4 & 1)) << 4) | l15;
      int src1 = src0 + 16;
      bool hiSel = (l4 >> 1) & 1;
      #pragma unroll
      for (int kc = 0; kc < 2; ++kc) {
        int A0 = __shfl((int)pk[kc * 2][0], src0);
        int A1 = __shfl((int)pk[kc * 2][1], src0);
        int A2 = __shfl((int)pk[kc * 2][0], src1);
        int A3 = __shfl((int)pk[kc * 2][1], src1);
        int B0 = __shfl((int)pk[kc * 2 + 1][0], src0);
        int B1 = __shfl((int)pk[kc * 2 + 1][1], src0);
        int B2 = __shfl((int)pk[kc * 2 + 1][0], src1);
        int B3 = __shfl((int)pk[kc * 2 + 1][1], src1);
        union { int i[4]; v8s v; } u;
        u.i[0] = hiSel ? B0 : A0;
        u.i[1] = hiSel ? B1 : A1;
        u.i[2] = hiSel ? B2 : A2;
        u.i[3] = hiSel ? B3 : A3;
        #pragma unroll
        for (int db = 0; db < 4; ++db) {
          int d = db * 16 + l15;
          v8s vf = *(const v8s*)(Vb + d * 128 + (((kc * 4 + l4) ^ (d & 7)) << 4));
          accO[db] = __builtin_amdgcn_mfma_f32_16x16x32_bf16(vf, u.v, accO[db], 0, 0, 0);
        }
      }
    }
    __syncthreads();
  }

  // normalize + write O[t][h*64+d] bf16
  float inv = 1.f / lsm;
  size_t orow = (size_t)(b * Tn + qw0 + l15) * 1024 + h * 64;
  #pragma unroll
  for (int db = 0; db < 4; ++db) {
    int d0 = db * 16 + l4 * 4;
    ushort4 ov;
    ov.x = f2bf(accO[db][0] * inv);
    ov.y = f2bf(accO[db][1] * inv);
    ov.z = f2bf(accO[db][2] * inv);
    ov.w = f2bf(accO[db][3] * inv);
    *(ushort4*)(o + orow + d0) = ov;
  }
}

extern "C" void kernel_launch(void* const* d_in, const int* in_sizes, int n_in,
                              void* d_out, int out_size, void* d_ws, size_t ws_size,
                              hipStream_t stream) {
  const float* x  = (const float*)d_in[0];
  const float* Wq = (const float*)d_in[1];
  const float* bq = (const float*)d_in[2];
  const float* Wk = (const float*)d_in[3];
  const float* bk = (const float*)d_in[4];
  const float* Wv = (const float*)d_in[5];
  const float* bv = (const float*)d_in[6];
  const float* Wo = (const float*)d_in[7];
  const float* bo = (const float*)d_in[8];
  const int*   pos = (const int*)d_in[9];
  float* out = (float*)d_out;

  char* ws = (char*)d_ws;
  unsigned short* xb      = (unsigned short*)(ws);                        // 8388608 B (reused as attno)
  unsigned short* wt_qkv  = (unsigned short*)(ws + 8388608);              // 3145728 B
  unsigned short* wt_o    = (unsigned short*)(ws + 11534336);             // 2097152 B
  float*          bias_q  = (float*)(ws + 13631488);                      // 6144 B
  float2*         table   = (float2*)(ws + 13637632);                     // 524288 B
  unsigned short* qkvb    = (unsigned short*)(ws + 14161920);             // 12582912 B
  unsigned short* vt      = (unsigned short*)(ws + 26744832);             // 2097152 B
  unsigned short* attno   = xb;                                           // reuse (x bf16 dead after GEMM1)

  // weights transpose + rope table + bias + x convert, one launch
  k_transpose_all<<<dim3(32, 32, 6), dim3(32, 8), 0, stream>>>(Wq, Wk, Wv, Wo, wt_qkv, wt_o,
                                                               pos, table, bq, bk, bv, bias_q,
                                                               x, xb);
  // qkv = x @ [Wq|Wk|Wv] + bias; q,k -> RoPE'd bf16 in qkvb, v -> vt transposed
  k_gemm_bt<false><<<dim3(12, 64), 256, 0, stream>>>(xb, wt_qkv, bias_q, table, nullptr, qkvb, vt,
                                                     4096, NQKV, 1024);
  // attention (load-balanced 1D grid)
  k_attn<<<512, 512, 0, stream>>>(qkvb, vt, attno);
  // out = attn @ Wo + bo  (f32 out)
  k_gemm_bt<true><<<dim3(8, 64), 256, 0, stream>>>(attno, wt_o, bo, nullptr, out, nullptr, nullptr,
                                                   4096, 1024, 1024);
}

// Round 6
// 77.415 us; speedup vs baseline: 1.6348x; 1.1668x over previous
//
#include <hip/hip_runtime.h>
#include <stdint.h>
#include <math.h>

typedef short v8s __attribute__((ext_vector_type(8)));
typedef float v4f __attribute__((ext_vector_type(4)));

#define DEVI static __device__ __forceinline__
#define AS1 __attribute__((address_space(1)))
#define AS3 __attribute__((address_space(3)))

static constexpr int Bn = 2;
static constexpr int Tn = 2048;
static constexpr int Hn = 16;
static constexpr int Gn = 4;
static constexpr int NQKV = 1536;   // H*D + 2*G*D
static constexpr int WIN = 512;
static constexpr int SINKN = 4;
#define SCALE_L2E (0.125f * 1.4426950408889634f)   // D^-0.5 * log2(e), folded into Wq/bq

DEVI unsigned short f2bf(float f) {
  unsigned u = __float_as_uint(f);
  u += 0x7fffu + ((u >> 16) & 1u);
  return (unsigned short)(u >> 16);
}
DEVI float bf2f(unsigned short h) { return __uint_as_float(((unsigned)h) << 16); }
// pack two f32 -> bf16x2 by truncation: low short = lo, high short = hi
DEVI unsigned pack_bf2(float hi, float lo) {
  return __builtin_amdgcn_perm(__float_as_uint(hi), __float_as_uint(lo), 0x07060302u);
}

// ------------- weights transpose + rope table + bias + x-convert, one launch -------------
// z: 0=Wq(scale) 1=Wk 2=Wv 3=Wo 4=rope-table+bias-concat 5=x fp32->bf16
__global__ __launch_bounds__(256) void k_transpose_all(const float* __restrict__ Wq,
                                                       const float* __restrict__ Wk,
                                                       const float* __restrict__ Wv,
                                                       const float* __restrict__ Wo,
                                                       unsigned short* __restrict__ wt_qkv,
                                                       unsigned short* __restrict__ wt_o,
                                                       const int* __restrict__ posp,
                                                       float2* __restrict__ table,
                                                       const float* __restrict__ bq,
                                                       const float* __restrict__ bk,
                                                       const float* __restrict__ bv,
                                                       float* __restrict__ biasout,
                                                       const float* __restrict__ x,
                                                       unsigned short* __restrict__ xb) {
  int z = blockIdx.z;
  int tx = threadIdx.x, ty = threadIdx.y;   // block (32,8)
  if (z == 5) {
    // x -> bf16, 4 float4 per thread (1024 blocks * 256 thr * 4 = 1,048,576 float4)
    int base = (blockIdx.y * 32 + blockIdx.x) * 256 + ty * 32 + tx;
    #pragma unroll
    for (int j = 0; j < 4; ++j) {
      int i = base + j * 262144;
      float4 v = ((const float4*)x)[i];
      ushort4 o;
      o.x = f2bf(v.x); o.y = f2bf(v.y); o.z = f2bf(v.z); o.w = f2bf(v.w);
      ((ushort4*)xb)[i] = o;
    }
    return;
  }
  if (z == 4) {
    int i = (blockIdx.y * 32 + blockIdx.x) * 256 + ty * 32 + tx;
    if (i < Tn * 32) {
      int t = i >> 5, d2 = i & 31;
      float inv = powf(10000.f, -(float)d2 / 32.f);
      float theta = (float)(posp[0] + t) * inv;
      float s, c;
      sincosf(theta, &s, &c);
      table[i] = make_float2(c, s);
    }
    if (i < NQKV)
      biasout[i] = (i < 1024) ? bq[i] * SCALE_L2E : (i < 1280 ? bk[i - 1024] : bv[i - 1280]);
    return;
  }
  const float* W; unsigned short* Wt; int N; float scale = 1.f;
  if (z == 0)      { W = Wq; Wt = wt_qkv;                 N = 1024; scale = SCALE_L2E; }
  else if (z == 1) { W = Wk; Wt = wt_qkv + 1024 * 1024;   N = 256; }
  else if (z == 2) { W = Wv; Wt = wt_qkv + 1280 * 1024;   N = 256; }
  else             { W = Wo; Wt = wt_o;                   N = 1024; }
  int n0 = blockIdx.x * 32, k0 = blockIdx.y * 32;
  if (n0 >= N) return;
  __shared__ float tile[32][33];
  #pragma unroll
  for (int yy = 0; yy < 4; ++yy)
    tile[ty + yy * 8][tx] = W[(size_t)(k0 + ty + yy * 8) * N + n0 + tx];
  __syncthreads();
  #pragma unroll
  for (int yy = 0; yy < 4; ++yy)
    Wt[(size_t)(n0 + ty + yy * 8) * 1024 + k0 + tx] = f2bf(tile[tx][ty + yy * 8] * scale);
}

// ---------------- GEMM: C[M][N] = A[M][K](bf16) * Bt[N][K]^T + bias ----------------
// 64x128 tile, BK=64, 4 waves (2 wm x 2 wn), single-buffer 2-barrier per K-step.
// LDS tiles XOR-swizzled (16B chunk ^= row&7) via pre-swizzled global source (T2/rule21).
// XCD-aware tile swizzle (nwg % 8 == 0 required).
template <bool F32OUT>
__global__ __launch_bounds__(256) void k_gemm_bt(const unsigned short* __restrict__ A,
                                                 const unsigned short* __restrict__ Bt,
                                                 const float* __restrict__ bias,
                                                 const float2* __restrict__ table,
                                                 float* __restrict__ outF,
                                                 unsigned short* __restrict__ outH,
                                                 unsigned short* __restrict__ vtH,
                                                 int M, int N, int K) {
  __shared__ char As[8192];     // [64 rows][128 B] (64 bf16)
  __shared__ char Bs[16384];    // [128 rows][128 B]
  int nx = gridDim.x;
  int nwg = nx * gridDim.y;
  int id = blockIdx.y * nx + blockIdx.x;
  int swz = (id & 7) * (nwg >> 3) + (id >> 3);
  int m0 = (swz / nx) * 64, n0 = (swz % nx) * 128;

  int t = threadIdx.x, lane = t & 63, wave = t >> 6;
  int wm = wave >> 1, wn = wave & 1;
  int l15 = lane & 15, l4 = lane >> 4;
  int l7 = l15 & 7;
  v4f acc[2][4] = {};

  for (int k0 = 0; k0 < K; k0 += 64) {
    __syncthreads();
    #pragma unroll
    for (int p = 0; p < 2; ++p) {     // A: 512 chunks of 16B
      int cid = p * 256 + t;
      int row = cid >> 3, cc = cid & 7;
      const unsigned short* ga = A + (size_t)(m0 + row) * K + k0 + (cc ^ (row & 7)) * 8;
      __builtin_amdgcn_global_load_lds((const AS1 void*)ga,
                                       (AS3 void*)(As + p * 4096 + wave * 1024), 16, 0, 0);
    }
    #pragma unroll
    for (int p = 0; p < 4; ++p) {     // B: 1024 chunks of 16B
      int cid = p * 256 + t;
      int row = cid >> 3, cc = cid & 7;
      const unsigned short* gb = Bt + (size_t)(n0 + row) * K + k0 + (cc ^ (row & 7)) * 8;
      __builtin_amdgcn_global_load_lds((const AS1 void*)gb,
                                       (AS3 void*)(Bs + p * 4096 + wave * 1024), 16, 0, 0);
    }
    __syncthreads();
    #pragma unroll
    for (int kk = 0; kk < 2; ++kk) {
      v8s af[2], bfr[4];
      #pragma unroll
      for (int mi = 0; mi < 2; ++mi)
        af[mi] = *(const v8s*)(As + (wm * 32 + mi * 16 + l15) * 128 + (((kk * 4 + l4) ^ l7) << 4));
      #pragma unroll
      for (int ni = 0; ni < 4; ++ni)
        bfr[ni] = *(const v8s*)(Bs + (wn * 64 + ni * 16 + l15) * 128 + (((kk * 4 + l4) ^ l7) << 4));
      #pragma unroll
      for (int mi = 0; mi < 2; ++mi)
        #pragma unroll
        for (int ni = 0; ni < 4; ++ni)
          acc[mi][ni] = __builtin_amdgcn_mfma_f32_16x16x32_bf16(af[mi], bfr[ni], acc[mi][ni], 0, 0, 0);
    }
  }

  if (!F32OUT && n0 >= 1280) {
    // v columns -> Vt[b][g][d][t], 4 contiguous t per lane
    #pragma unroll
    for (int mi = 0; mi < 2; ++mi) {
      #pragma unroll
      for (int ni = 0; ni < 4; ++ni) {
        int col = n0 + wn * 64 + ni * 16 + l15;
        float bv = bias[col];
        int c2 = col - 1280;
        int gg = c2 >> 6, dd = c2 & 63;
        int row = m0 + wm * 32 + mi * 16 + l4 * 4;
        int bb = row >> 11, tt = row & 2047;
        ushort4 ov;
        ov.x = f2bf(acc[mi][ni][0] + bv);
        ov.y = f2bf(acc[mi][ni][1] + bv);
        ov.z = f2bf(acc[mi][ni][2] + bv);
        ov.w = f2bf(acc[mi][ni][3] + bv);
        *(ushort4*)(vtH + ((size_t)((bb * Gn + gg) * 64 + dd)) * Tn + tt) = ov;
      }
    }
  } else if (!F32OUT) {
    // q/k region: fused interleaved RoPE. col parity == lane parity, partner = lane^1.
    #pragma unroll
    for (int mi = 0; mi < 2; ++mi) {
      #pragma unroll
      for (int ni = 0; ni < 4; ++ni) {
        int col = n0 + wn * 64 + ni * 16 + l15;
        float bv = bias[col];
        int d2 = (col & 63) >> 1;
        bool even = !(col & 1);
        #pragma unroll
        for (int r = 0; r < 4; ++r) {
          int row = m0 + wm * 32 + mi * 16 + l4 * 4 + r;
          int tt = row & 2047;
          float2 cs = table[tt * 32 + d2];
          float v = acc[mi][ni][r] + bv;
          float prt = __shfl_xor(v, 1);
          float ov = even ? (v * cs.x - prt * cs.y) : (prt * cs.y + v * cs.x);
          outH[(size_t)row * N + col] = f2bf(ov);
        }
      }
    }
  } else {
    #pragma unroll
    for (int mi = 0; mi < 2; ++mi) {
      #pragma unroll
      for (int ni = 0; ni < 4; ++ni) {
        int col = n0 + wn * 64 + ni * 16 + l15;
        float bv = bias[col];
        #pragma unroll
        for (int r = 0; r < 4; ++r) {
          int row = m0 + wm * 32 + mi * 16 + l4 * 4 + r;
          outF[(size_t)row * N + col] = acc[mi][ni][r] + bv;
        }
      }
    }
  }
}

// ---------------- Flash attention, GQA + sliding window + sink ----------------
// 1D grid of 512 blocks, 512 thr = 8 waves, wave w owns q rows [qt0+16w, qt0+16w+16).
// Load-balance pairing: b=1 half gets the reversed q-tile index.
// Swapped QK^T: S^T = mfma(K,Q); O^T = mfma(V^T, P^T). K and V^T double-buffered.
// P redistribution via per-wave swizzled LDS buffer (no cross-wave sync needed).
__global__ __launch_bounds__(512) void k_attn(const unsigned short* __restrict__ qkv,
                                              const unsigned short* __restrict__ vt,
                                              unsigned short* __restrict__ o) {
  __shared__ char smem[2 * 16384 + 16384];    // 2 bufs (K 8KB | V^T 8KB) + 8 waves x 2KB P
  int id = blockIdx.x;
  int half = id >> 8, r5 = id & 255;
  int h = r5 >> 4;
  int qtile = half ? (15 - (r5 & 15)) : (r5 & 15);
  int b = half;
  int qt0 = qtile * 128;
  int g = h >> 2;
  int t = threadIdx.x, lane = t & 63, wave = t >> 6;
  int l15 = lane & 15, l4 = lane >> 4;
  int l7 = l15 & 7;
  int qw0 = qt0 + wave * 16;
  char* Pb = smem + 32768 + wave * 2048;

  // tile schedule
  int jt_end = (qt0 + 127) >> 6;
  int wstart = (qt0 > WIN) ? ((qt0 - WIN) >> 6) : 0;
  int nIt = (wstart > 0) ? (jt_end - wstart + 2) : (jt_end + 1);

  // staging source coords (per thread, 1 x 16B per matrix)
  int sr = t >> 3, sc = t & 7;
  int scs = (sc ^ (sr & 7)) << 3;   // pre-swizzled element offset
  const unsigned short* gkb = qkv + (size_t)(b * Tn + sr) * NQKV + 1024 + g * 64 + scs;
  const unsigned short* gvb = vt + ((size_t)((b * Gn + g) * 64 + sr)) * Tn + scs;

  auto stageKV = [&](int buf, int j0) {
    __builtin_amdgcn_global_load_lds((const AS1 void*)(gkb + (size_t)j0 * NQKV),
                                     (AS3 void*)(smem + buf * 16384 + wave * 1024), 16, 0, 0);
    __builtin_amdgcn_global_load_lds((const AS1 void*)(gvb + j0),
                                     (AS3 void*)(smem + buf * 16384 + 8192 + wave * 1024), 16, 0, 0);
  };

  auto jt_of = [&](int it) { return (wstart > 0) ? (it == 0 ? 0 : wstart + it - 1) : it; };

  stageKV(0, jt_of(0) << 6);

  // Q fragments direct from global (post-RoPE, scale pre-folded)
  v8s Qf[2];
  #pragma unroll
  for (int hf = 0; hf < 2; ++hf)
    Qf[hf] = *(const v8s*)(qkv + (size_t)(b * Tn + qw0 + l15) * NQKV + h * 64 + hf * 32 + l4 * 8);

  float m = -INFINITY, lsm = 0.f;
  v4f accO[4] = {};

  __syncthreads();

  for (int it = 0; it < nIt; ++it) {
    int cur = it & 1;
    if (it + 1 < nIt) stageKV(cur ^ 1, jt_of(it + 1) << 6);
    int j0 = jt_of(it) << 6;

    bool skip = (j0 > qw0 + 15) || ((j0 + 63 < qw0 - WIN) && (j0 >= SINKN));
    if (!skip) {
      const char* Kb = smem + cur * 16384;
      const char* Vb = Kb + 8192;
      // S^T[key][q]
      v4f s[4];
      __builtin_amdgcn_s_setprio(1);
      #pragma unroll
      for (int kb = 0; kb < 4; ++kb) {
        int r = kb * 16 + l15;
        v8s kf0 = *(const v8s*)(Kb + r * 128 + ((l4 ^ (r & 7)) << 4));
        v8s kf1 = *(const v8s*)(Kb + r * 128 + (((4 + l4) ^ (r & 7)) << 4));
        v4f z = {};
        z = __builtin_amdgcn_mfma_f32_16x16x32_bf16(kf0, Qf[0], z, 0, 0, 0);
        s[kb] = __builtin_amdgcn_mfma_f32_16x16x32_bf16(kf1, Qf[1], z, 0, 0, 0);
      }
      __builtin_amdgcn_s_setprio(0);
      bool needMask = !((j0 + 63 <= qw0) && (j0 >= qw0 + 15 - WIN));
      if (needMask) {
        #pragma unroll
        for (int kb = 0; kb < 4; ++kb)
          #pragma unroll
          for (int r = 0; r < 4; ++r) {
            int j = j0 + kb * 16 + l4 * 4 + r;
            int qg = qw0 + l15;
            bool valid = (j <= qg) && ((j >= qg - WIN) || (j < SINKN));
            s[kb][r] = valid ? s[kb][r] : -1e30f;
          }
      }
      float mt = -1e30f;
      #pragma unroll
      for (int kb = 0; kb < 4; ++kb)
        #pragma unroll
        for (int r = 0; r < 4; ++r) mt = fmaxf(mt, s[kb][r]);
      mt = fmaxf(mt, __shfl_xor(mt, 16));
      mt = fmaxf(mt, __shfl_xor(mt, 32));
      if (!__all(mt <= m + 8.f)) {      // T13 defer-max
        float mnew = fmaxf(m, mt);
        float alpha = exp2f(m - mnew);  // first tile: exp2(-inf)=0
        lsm *= alpha;
        #pragma unroll
        for (int db = 0; db < 4; ++db) {
          accO[db][0] *= alpha; accO[db][1] *= alpha;
          accO[db][2] *= alpha; accO[db][3] *= alpha;
        }
        m = mnew;
      }
      float lsum = 0.f;
      #pragma unroll
      for (int kb = 0; kb < 4; ++kb) {
        float p0 = exp2f(s[kb][0] - m);
        float p1 = exp2f(s[kb][1] - m);
        float p2 = exp2f(s[kb][2] - m);
        float p3 = exp2f(s[kb][3] - m);
        lsum += (p0 + p1) + (p2 + p3);
        unsigned lo = pack_bf2(p1, p0);
        unsigned hi = pack_bf2(p3, p2);
        // P[q=l15][key=kb*16+l4*4 .. +3], swizzled 16B chunks within 128B row
        unsigned long long w = ((unsigned long long)hi << 32) | lo;
        *(unsigned long long*)(Pb + l15 * 128 + ((kb * 32 + l4 * 8) ^ (l7 << 4))) = w;
      }
      lsum += __shfl_xor(lsum, 16);
      lsum += __shfl_xor(lsum, 32);
      lsm += lsum;
      // same-wave cross-lane LDS dependency: drain writes, pin ordering
      asm volatile("s_waitcnt lgkmcnt(0)" ::: "memory");
      __builtin_amdgcn_sched_barrier(0);

      // PV: B-frag = P[q=l15][key = kc*32 + l4*8 + i] read directly from Pb
      __builtin_amdgcn_s_setprio(1);
      #pragma unroll
      for (int kc = 0; kc < 2; ++kc) {
        v8s pfrag = *(const v8s*)(Pb + l15 * 128 + ((kc * 64 + l4 * 16) ^ (l7 << 4)));
        #pragma unroll
        for (int db = 0; db < 4; ++db) {
          int d = db * 16 + l15;
          v8s vf = *(const v8s*)(Vb + d * 128 + (((kc * 4 + l4) ^ (d & 7)) << 4));
          accO[db] = __builtin_amdgcn_mfma_f32_16x16x32_bf16(vf, pfrag, accO[db], 0, 0, 0);
        }
      }
      __builtin_amdgcn_s_setprio(0);
    }
    __syncthreads();
  }

  // normalize + write O[t][h*64+d] bf16
  float inv = 1.f / lsm;
  size_t orow = (size_t)(b * Tn + qw0 + l15) * 1024 + h * 64;
  #pragma unroll
  for (int db = 0; db < 4; ++db) {
    int d0 = db * 16 + l4 * 4;
    ushort4 ov;
    ov.x = f2bf(accO[db][0] * inv);
    ov.y = f2bf(accO[db][1] * inv);
    ov.z = f2bf(accO[db][2] * inv);
    ov.w = f2bf(accO[db][3] * inv);
    *(ushort4*)(o + orow + d0) = ov;
  }
}

extern "C" void kernel_launch(void* const* d_in, const int* in_sizes, int n_in,
                              void* d_out, int out_size, void* d_ws, size_t ws_size,
                              hipStream_t stream) {
  const float* x  = (const float*)d_in[0];
  const float* Wq = (const float*)d_in[1];
  const float* bq = (const float*)d_in[2];
  const float* Wk = (const float*)d_in[3];
  const float* bk = (const float*)d_in[4];
  const float* Wv = (const float*)d_in[5];
  const float* bv = (const float*)d_in[6];
  const float* Wo = (const float*)d_in[7];
  const float* bo = (const float*)d_in[8];
  const int*   pos = (const int*)d_in[9];
  float* out = (float*)d_out;

  char* ws = (char*)d_ws;
  unsigned short* xb      = (unsigned short*)(ws);                        // 8388608 B (reused as attno)
  unsigned short* wt_qkv  = (unsigned short*)(ws + 8388608);              // 3145728 B
  unsigned short* wt_o    = (unsigned short*)(ws + 11534336);             // 2097152 B
  float*          bias_q  = (float*)(ws + 13631488);                      // 6144 B
  float2*         table   = (float2*)(ws + 13637632);                     // 524288 B
  unsigned short* qkvb    = (unsigned short*)(ws + 14161920);             // 12582912 B
  unsigned short* vt      = (unsigned short*)(ws + 26744832);             // 2097152 B
  unsigned short* attno   = xb;                                           // reuse (x bf16 dead after GEMM1)

  // weights transpose + rope table + bias + x convert, one launch
  k_transpose_all<<<dim3(32, 32, 6), dim3(32, 8), 0, stream>>>(Wq, Wk, Wv, Wo, wt_qkv, wt_o,
                                                               pos, table, bq, bk, bv, bias_q,
                                                               x, xb);
  // qkv = x @ [Wq|Wk|Wv] + bias; q,k -> RoPE'd bf16 in qkvb, v -> vt transposed
  k_gemm_bt<false><<<dim3(12, 64), 256, 0, stream>>>(xb, wt_qkv, bias_q, table, nullptr, qkvb, vt,
                                                     4096, NQKV, 1024);
  // attention (load-balanced 1D grid)
  k_attn<<<512, 512, 0, stream>>>(qkvb, vt, attno);
  // out = attn @ Wo + bo  (f32 out)
  k_gemm_bt<true><<<dim3(8, 64), 256, 0, stream>>>(attno, wt_o, bo, nullptr, out, nullptr, nullptr,
                                                   4096, 1024, 1024);
}